// Round 1
// baseline (2145.515 us; speedup 1.0000x reference)
//
#include <hip/hip_runtime.h>
#include <math.h>

// Problem constants
#define NB 32768   // batch
// D=256, N=4, OUT=512, H=4, DH=64

typedef unsigned short u16;

__device__ __forceinline__ float bf2f(u16 u){ return __uint_as_float(((unsigned int)u)<<16); }
__device__ __forceinline__ u16 f2bf(float f){
    unsigned int x = __float_as_uint(f);
    x += 0x7fffu + ((x>>16)&1u);   // round-to-nearest-even
    return (u16)(x>>16);
}
__device__ __forceinline__ float gelu_f(float x){ return 0.5f*x*(1.0f+erff(x*0.70710678118654752f)); }

// ---------------- prep: wcat[b][n][d] = w_n[b][d] * softmax(tfw)[n]  (bf16) ----------------
__global__ __launch_bounds__(256) void prep_kernel(
    const float* __restrict__ w0, const float* __restrict__ w1,
    const float* __restrict__ w2, const float* __restrict__ w3,
    const float* __restrict__ tfw, u16* __restrict__ wcat)
{
    float t0=tfw[0], t1=tfw[1], t2=tfw[2], t3=tfw[3];
    float m = fmaxf(fmaxf(t0,t1), fmaxf(t2,t3));
    float e0=expf(t0-m), e1=expf(t1-m), e2=expf(t2-m), e3=expf(t3-m);
    float inv = 1.0f/(e0+e1+e2+e3);
    float s0=e0*inv, s1=e1*inv, s2=e2*inv, s3=e3*inv;

    int idx = blockIdx.x*256 + threadIdx.x;      // B*64 threads, 4 d's each
    int b  = idx >> 6;
    int d4 = (idx & 63) << 2;
    size_t src = (size_t)b*256 + d4;
    float4 a0 = *reinterpret_cast<const float4*>(w0 + src);
    float4 a1 = *reinterpret_cast<const float4*>(w1 + src);
    float4 a2 = *reinterpret_cast<const float4*>(w2 + src);
    float4 a3 = *reinterpret_cast<const float4*>(w3 + src);
    size_t dst = (size_t)b*1024 + d4;
    ushort4 o;
    o.x=f2bf(a0.x*s0); o.y=f2bf(a0.y*s0); o.z=f2bf(a0.z*s0); o.w=f2bf(a0.w*s0);
    *reinterpret_cast<ushort4*>(wcat + dst) = o;
    o.x=f2bf(a1.x*s1); o.y=f2bf(a1.y*s1); o.z=f2bf(a1.z*s1); o.w=f2bf(a1.w*s1);
    *reinterpret_cast<ushort4*>(wcat + dst + 256) = o;
    o.x=f2bf(a2.x*s2); o.y=f2bf(a2.y*s2); o.z=f2bf(a2.z*s2); o.w=f2bf(a2.w*s2);
    *reinterpret_cast<ushort4*>(wcat + dst + 512) = o;
    o.x=f2bf(a3.x*s3); o.y=f2bf(a3.y*s3); o.z=f2bf(a3.z*s3); o.w=f2bf(a3.w*s3);
    *reinterpret_cast<ushort4*>(wcat + dst + 768) = o;
}

// ---------------- generic tiled GEMM: C[M,N] = act(A[M,K](bf16) @ W[N,K]^T + bias) -> bf16 ----------------
// BM=BN=64, BK=16, 256 threads, 4x4 per thread. Requires M%64==0, N%64==0, K%16==0.
template<int ACT>   // 0 = none, 1 = exact gelu
__global__ __launch_bounds__(256) void gemm_kernel(
    const u16* __restrict__ A, int lda,
    const float* __restrict__ W, const float* __restrict__ bias,
    u16* __restrict__ C, int ldc, int M, int N, int K)
{
    __shared__ float As[16][64];
    __shared__ float Ws[16][64];
    const int tid = threadIdx.x;
    const int row0 = blockIdx.x*64, col0 = blockIdx.y*64;
    const int tx = tid & 15, ty = tid >> 4;
    const int sm = tid >> 2;          // 0..63
    const int sk = (tid & 3) << 2;    // 0,4,8,12
    const u16*   Ap = A + (size_t)(row0+sm)*lda + sk;
    const float* Wp = W + (size_t)(col0+sm)*K   + sk;
    float acc[4][4] = {};

    for (int k0 = 0; k0 < K; k0 += 16){
        ushort4 av = *reinterpret_cast<const ushort4*>(Ap + k0);
        float4  wv = *reinterpret_cast<const float4*>(Wp + k0);
        __syncthreads();
        As[sk+0][sm]=bf2f(av.x); As[sk+1][sm]=bf2f(av.y);
        As[sk+2][sm]=bf2f(av.z); As[sk+3][sm]=bf2f(av.w);
        Ws[sk+0][sm]=wv.x; Ws[sk+1][sm]=wv.y; Ws[sk+2][sm]=wv.z; Ws[sk+3][sm]=wv.w;
        __syncthreads();
        #pragma unroll
        for (int kk=0; kk<16; ++kk){
            float ar[4], wr[4];
            #pragma unroll
            for (int i=0;i<4;i++) ar[i] = As[kk][(ty<<2)+i];
            #pragma unroll
            for (int j=0;j<4;j++) wr[j] = Ws[kk][(tx<<2)+j];
            #pragma unroll
            for (int i=0;i<4;i++)
                #pragma unroll
                for (int j=0;j<4;j++)
                    acc[i][j] += ar[i]*wr[j];
        }
    }

    float bb[4];
    #pragma unroll
    for (int j=0;j<4;j++) bb[j] = bias[col0+(tx<<2)+j];
    #pragma unroll
    for (int i=0;i<4;i++){
        ushort4 o;
        float v0 = acc[i][0]+bb[0], v1 = acc[i][1]+bb[1], v2 = acc[i][2]+bb[2], v3 = acc[i][3]+bb[3];
        if (ACT==1){ v0=gelu_f(v0); v1=gelu_f(v1); v2=gelu_f(v2); v3=gelu_f(v3); }
        o.x=f2bf(v0); o.y=f2bf(v1); o.z=f2bf(v2); o.w=f2bf(v3);
        *reinterpret_cast<ushort4*>(C + (size_t)(row0+(ty<<2)+i)*ldc + col0 + (tx<<2)) = o;
    }
}

// ---------------- attention (N=4 keys, H=4 heads, DH=64): ctx written over q buffer ----------------
__global__ __launch_bounds__(256) void attn_kernel(
    const u16* __restrict__ q, const u16* __restrict__ k, const u16* __restrict__ v,
    u16* __restrict__ ctx)
{
    __shared__ float sQ[256], sK[1024], sV[1024], sS[16], sA[16];
    const int b = blockIdx.x, t = threadIdx.x;
    sQ[t] = bf2f(q[(size_t)b*256 + t]);
    #pragma unroll
    for (int n=0;n<4;n++){
        sK[n*256+t] = bf2f(k[(size_t)b*1024 + n*256 + t]);
        sV[n*256+t] = bf2f(v[(size_t)b*1024 + n*256 + t]);
    }
    __syncthreads();
    if (t < 16){
        int h = t>>2, n = t&3;
        float s = 0.f;
        const int o = h*64;
        #pragma unroll
        for (int dh=0; dh<64; ++dh) s += sQ[o+dh]*sK[n*256+o+dh];
        sS[t] = s * 0.125f;   // 1/sqrt(64)
    }
    __syncthreads();
    if (t < 4){
        float a0=sS[t*4+0], a1=sS[t*4+1], a2=sS[t*4+2], a3=sS[t*4+3];
        float m = fmaxf(fmaxf(a0,a1), fmaxf(a2,a3));
        float e0=expf(a0-m), e1=expf(a1-m), e2=expf(a2-m), e3=expf(a3-m);
        float inv = 1.0f/(e0+e1+e2+e3);
        sA[t*4+0]=e0*inv; sA[t*4+1]=e1*inv; sA[t*4+2]=e2*inv; sA[t*4+3]=e3*inv;
    }
    __syncthreads();
    const int h = t>>6;
    float c = sA[h*4+0]*sV[t] + sA[h*4+1]*sV[256+t] + sA[h*4+2]*sV[512+t] + sA[h*4+3]*sV[768+t];
    ctx[(size_t)b*256 + t] = f2bf(c);
}

// ---------------- entry = LN(query + attn_out)*(1+gamma)+beta, overwrites wcat[b][0] ----------------
__global__ __launch_bounds__(256) void lnfilm_kernel(
    u16* __restrict__ wcat, const u16* __restrict__ ao, const float* __restrict__ regime,
    const float* __restrict__ sgw, const float* __restrict__ sgb,
    const float* __restrict__ sbw, const float* __restrict__ sbb,
    const float* __restrict__ g1, const float* __restrict__ b1)
{
    const int b = blockIdx.x, t = threadIdx.x;
    float x = bf2f(wcat[(size_t)b*1024 + t]) + bf2f(ao[(size_t)b*256 + t]);
    float s = x, q = x*x;
    #pragma unroll
    for (int o=32;o;o>>=1){ s += __shfl_xor(s,o); q += __shfl_xor(q,o); }
    __shared__ float rs[4], rq[4];
    if ((t&63)==0){ rs[t>>6]=s; rq[t>>6]=q; }
    __syncthreads();
    s = rs[0]+rs[1]+rs[2]+rs[3];
    q = rq[0]+rq[1]+rq[2]+rq[3];
    float mu  = s*(1.0f/256.0f);
    float var = q*(1.0f/256.0f) - mu*mu;
    float rstd = rsqrtf(var + 1e-5f);
    float r0=regime[b*4+0], r1=regime[b*4+1], r2=regime[b*4+2], r3=regime[b*4+3];
    float gam = r0*sgw[t*4+0]+r1*sgw[t*4+1]+r2*sgw[t*4+2]+r3*sgw[t*4+3]+sgb[t];
    float bet = r0*sbw[t*4+0]+r1*sbw[t*4+1]+r2*sbw[t*4+2]+r3*sbw[t*4+3]+sbb[t];
    float e = ((x-mu)*rstd*g1[t]+b1[t])*(1.0f+gam)+bet;
    wcat[(size_t)b*1024 + t] = f2bf(e);
}

// ---------------- fused = LN(t1) -> f32 out ----------------
__global__ __launch_bounds__(256) void ln2_kernel(
    const u16* __restrict__ t1, const float* __restrict__ g, const float* __restrict__ bt,
    float* __restrict__ out)
{
    const int b = blockIdx.x, t = threadIdx.x;
    float x0 = bf2f(t1[(size_t)b*512 + t]);
    float x1 = bf2f(t1[(size_t)b*512 + 256 + t]);
    float s = x0+x1, q = x0*x0 + x1*x1;
    #pragma unroll
    for (int o=32;o;o>>=1){ s += __shfl_xor(s,o); q += __shfl_xor(q,o); }
    __shared__ float rs[4], rq[4];
    if ((t&63)==0){ rs[t>>6]=s; rq[t>>6]=q; }
    __syncthreads();
    s = rs[0]+rs[1]+rs[2]+rs[3];
    q = rq[0]+rq[1]+rq[2]+rq[3];
    float mu  = s*(1.0f/512.0f);
    float var = q*(1.0f/512.0f) - mu*mu;
    float rstd = rsqrtf(var + 1e-5f);
    out[(size_t)b*512 + t]       = (x0-mu)*rstd*g[t]     + bt[t];
    out[(size_t)b*512 + 256 + t] = (x1-mu)*rstd*g[256+t] + bt[256+t];
}

// ---------------- alignment = sigmoid(a @ a2_w^T + a2_b) ----------------
__global__ __launch_bounds__(64) void a2_kernel(
    const u16* __restrict__ a, const float* __restrict__ a2w, const float* __restrict__ a2b,
    float* __restrict__ out)
{
    const int b = blockIdx.x, t = threadIdx.x;
    float s = bf2f(a[(size_t)b*128 + t])*a2w[t] + bf2f(a[(size_t)b*128 + 64 + t])*a2w[64+t];
    #pragma unroll
    for (int o=32;o;o>>=1) s += __shfl_xor(s,o);
    if (t==0) out[b] = 1.0f/(1.0f+expf(-(s + a2b[0])));
}

extern "C" void kernel_launch(void* const* d_in, const int* in_sizes, int n_in,
                              void* d_out, int out_size, void* d_ws, size_t ws_size,
                              hipStream_t stream) {
    const float* w0   = (const float*)d_in[0];
    const float* w1   = (const float*)d_in[1];
    const float* w2   = (const float*)d_in[2];
    const float* w3   = (const float*)d_in[3];
    const float* regime = (const float*)d_in[4];
    const float* tfw  = (const float*)d_in[5];
    const float* in_proj_w = (const float*)d_in[6];
    const float* in_proj_b = (const float*)d_in[7];
    const float* out_proj_w = (const float*)d_in[8];
    const float* out_proj_b = (const float*)d_in[9];
    const float* ln1_g = (const float*)d_in[10];
    const float* ln1_b = (const float*)d_in[11];
    const float* sg_w = (const float*)d_in[12];
    const float* sg_b = (const float*)d_in[13];
    const float* sb_w = (const float*)d_in[14];
    const float* sb_b = (const float*)d_in[15];
    const float* f1_w = (const float*)d_in[16];
    const float* f1_b = (const float*)d_in[17];
    const float* f2_w = (const float*)d_in[18];
    const float* f2_b = (const float*)d_in[19];
    const float* ln2_g = (const float*)d_in[20];
    const float* ln2_b = (const float*)d_in[21];
    const float* a1_w = (const float*)d_in[22];
    const float* a1_b = (const float*)d_in[23];
    const float* a2_w = (const float*)d_in[24];
    const float* a2_b = (const float*)d_in[25];

    char* ws = (char*)d_ws;
    // layout (bytes): wcat 64MiB | q/ctx 16MiB | k 64MiB | v 64MiB | ao 16MiB  => 224 MiB
    u16* wcat  = (u16*)(ws);
    u16* qbuf  = (u16*)(ws + 67108864ull);
    u16* kbuf  = (u16*)(ws + 83886080ull);
    u16* vbuf  = (u16*)(ws + 150994944ull);
    u16* aobuf = (u16*)(ws + 218103808ull);
    // aliases after attention phase:
    u16* hbuf  = kbuf;    // B x 1024 bf16
    u16* t1buf = vbuf;    // B x 512  bf16
    u16* abuf  = aobuf;   // B x 128  bf16

    float* out_fused = (float*)d_out;
    float* out_align = (float*)d_out + (size_t)NB*512;

    // 1. weighted (scaled) -> wcat
    prep_kernel<<<NB*64/256, 256, 0, stream>>>(w0,w1,w2,w3,tfw,wcat);
    // 2. q = query @ wq^T + bq   (A rows stride 1024, first 256 cols)
    gemm_kernel<0><<<dim3(NB/64, 4), 256, 0, stream>>>(wcat, 1024, in_proj_w,          in_proj_b,     qbuf, 256, NB,   256, 256);
    // 3. k = weighted @ wk^T + bk   (M = 4B rows of 256)
    gemm_kernel<0><<<dim3(NB*4/64, 4), 256, 0, stream>>>(wcat, 256, in_proj_w+65536,   in_proj_b+256, kbuf, 256, NB*4, 256, 256);
    // 4. v = weighted @ wv^T + bv
    gemm_kernel<0><<<dim3(NB*4/64, 4), 256, 0, stream>>>(wcat, 256, in_proj_w+131072,  in_proj_b+512, vbuf, 256, NB*4, 256, 256);
    // 5. attention -> ctx (overwrites qbuf)
    attn_kernel<<<NB, 256, 0, stream>>>(qbuf, kbuf, vbuf, qbuf);
    // 6. attn_out = ctx @ out_proj^T + b
    gemm_kernel<0><<<dim3(NB/64, 4), 256, 0, stream>>>(qbuf, 256, out_proj_w, out_proj_b, aobuf, 256, NB, 256, 256);
    // 7. entry = FiLM(LN(query+attn_out)) -> wcat[:,0:256]  (wcat becomes `cat`)
    lnfilm_kernel<<<NB, 256, 0, stream>>>(wcat, aobuf, regime, sg_w, sg_b, sb_w, sb_b, ln1_g, ln1_b);
    // 8. h = gelu(cat @ f1^T + b)  -> hbuf
    gemm_kernel<1><<<dim3(NB/64, 16), 256, 0, stream>>>(wcat, 1024, f1_w, f1_b, hbuf, 1024, NB, 1024, 1024);
    // 9. t1 = h @ f2^T + b
    gemm_kernel<0><<<dim3(NB/64, 8), 256, 0, stream>>>(hbuf, 1024, f2_w, f2_b, t1buf, 512, NB, 512, 1024);
    // 10. fused = LN(t1) -> out
    ln2_kernel<<<NB, 256, 0, stream>>>(t1buf, ln2_g, ln2_b, out_fused);
    // 11. a = gelu(cat @ a1^T + b)
    gemm_kernel<1><<<dim3(NB/64, 2), 256, 0, stream>>>(wcat, 1024, a1_w, a1_b, abuf, 128, NB, 128, 1024);
    // 12. alignment = sigmoid(a @ a2^T + b)
    a2_kernel<<<NB, 64, 0, stream>>>(abuf, a2_w, a2_b, out_align);
}

// Round 3
// 432.390 us; speedup vs baseline: 4.9620x; 4.9620x over previous
//
#include <hip/hip_runtime.h>
#include <math.h>

#define NB 32768   // batch
// D=256, N=4, OUT=512, H=4, DH=64

typedef unsigned short u16;
typedef __attribute__((ext_vector_type(4))) float f32x4;
typedef __attribute__((ext_vector_type(8))) short bf16x8;

__device__ __forceinline__ float bf2f(u16 u){ return __uint_as_float(((unsigned int)u)<<16); }
__device__ __forceinline__ u16 f2bf(float f){
    unsigned int x = __float_as_uint(f);
    x += 0x7fffu + ((x>>16)&1u);   // round-to-nearest-even
    return (u16)(x>>16);
}
__device__ __forceinline__ float gelu_f(float x){ return 0.5f*x*(1.0f+erff(x*0.70710678118654752f)); }

__device__ __forceinline__ void gload16(const void* g, void* l){
    __builtin_amdgcn_global_load_lds(
        (const __attribute__((address_space(1))) unsigned int*)g,
        (__attribute__((address_space(3))) unsigned int*)l, 16, 0, 0);
}

// ---------------- prep: wcat[b][n][d] = w_n[b][d] * softmax(tfw)[n]  (bf16) ----------------
__global__ __launch_bounds__(256) void prep_kernel(
    const float* __restrict__ w0, const float* __restrict__ w1,
    const float* __restrict__ w2, const float* __restrict__ w3,
    const float* __restrict__ tfw, u16* __restrict__ wcat)
{
    float t0=tfw[0], t1=tfw[1], t2=tfw[2], t3=tfw[3];
    float m = fmaxf(fmaxf(t0,t1), fmaxf(t2,t3));
    float e0=expf(t0-m), e1=expf(t1-m), e2=expf(t2-m), e3=expf(t3-m);
    float inv = 1.0f/(e0+e1+e2+e3);
    float s0=e0*inv, s1=e1*inv, s2=e2*inv, s3=e3*inv;

    int idx = blockIdx.x*256 + threadIdx.x;      // B*64 threads, 4 d's each
    int b  = idx >> 6;
    int d4 = (idx & 63) << 2;
    size_t src = (size_t)b*256 + d4;
    float4 a0 = *reinterpret_cast<const float4*>(w0 + src);
    float4 a1 = *reinterpret_cast<const float4*>(w1 + src);
    float4 a2 = *reinterpret_cast<const float4*>(w2 + src);
    float4 a3 = *reinterpret_cast<const float4*>(w3 + src);
    size_t dst = (size_t)b*1024 + d4;
    ushort4 o;
    o.x=f2bf(a0.x*s0); o.y=f2bf(a0.y*s0); o.z=f2bf(a0.z*s0); o.w=f2bf(a0.w*s0);
    *reinterpret_cast<ushort4*>(wcat + dst) = o;
    o.x=f2bf(a1.x*s1); o.y=f2bf(a1.y*s1); o.z=f2bf(a1.z*s1); o.w=f2bf(a1.w*s1);
    *reinterpret_cast<ushort4*>(wcat + dst + 256) = o;
    o.x=f2bf(a2.x*s2); o.y=f2bf(a2.y*s2); o.z=f2bf(a2.z*s2); o.w=f2bf(a2.w*s2);
    *reinterpret_cast<ushort4*>(wcat + dst + 512) = o;
    o.x=f2bf(a3.x*s3); o.y=f2bf(a3.y*s3); o.z=f2bf(a3.z*s3); o.w=f2bf(a3.w*s3);
    *reinterpret_cast<ushort4*>(wcat + dst + 768) = o;
}

// ---------------- weight fp32 -> bf16 conversion ----------------
__global__ __launch_bounds__(256) void conv1_kernel(const float* __restrict__ s, u16* __restrict__ d){
    int i = blockIdx.x*256 + threadIdx.x;
    float4 v = reinterpret_cast<const float4*>(s)[i];
    ushort4 o; o.x=f2bf(v.x); o.y=f2bf(v.y); o.z=f2bf(v.z); o.w=f2bf(v.w);
    reinterpret_cast<ushort4*>(d)[i] = o;
}

__global__ __launch_bounds__(256) void conv2_kernel(
    const float* __restrict__ s0, u16* __restrict__ d0,   // out_proj 16384 chunks
    const float* __restrict__ s1, u16* __restrict__ d1,   // f1       262144
    const float* __restrict__ s2, u16* __restrict__ d2,   // f2       131072
    const float* __restrict__ s3, u16* __restrict__ d3)   // a1       32768
{
    int i = blockIdx.x*256 + threadIdx.x;
    const float* s; u16* d; int off;
    if      (i < 16384) { s=s0; d=d0; off=i; }
    else if (i < 278528){ s=s1; d=d1; off=i-16384; }
    else if (i < 409600){ s=s2; d=d2; off=i-278528; }
    else                { s=s3; d=d3; off=i-409600; }
    float4 v = reinterpret_cast<const float4*>(s)[off];
    ushort4 o; o.x=f2bf(v.x); o.y=f2bf(v.y); o.z=f2bf(v.z); o.w=f2bf(v.w);
    reinterpret_cast<ushort4*>(d)[off] = o;
}

// ---------------- MFMA GEMM: C[M,N] = act(A[M,K] @ W[N,K]^T + bias), all bf16, fp32 acc ----------------
// 128x128 tile, BK=32, 256 threads = 4 waves, wave quadrant 64x64, 4x4 fragments of 16x16x32.
template<int ACT>   // 0 = none, 1 = exact gelu
__global__ __launch_bounds__(256) void mgemm_kernel(
    const u16* __restrict__ A, int lda,
    const u16* __restrict__ W, int ldw,
    const float* __restrict__ bias,
    u16* __restrict__ C, int ldc, int K)
{
    __shared__ __align__(16) u16 sA[4096];   // [128][32]
    __shared__ __align__(16) u16 sB[4096];   // [128][32]

    const int tid  = threadIdx.x;
    const int lane = tid & 63;
    const int wid  = tid >> 6;
    const int wr   = wid >> 1, wc = wid & 1;
    const int row0 = blockIdx.x << 7, col0 = blockIdx.y << 7;

    // staging: issue i covers tile elements e = (i*256 + tid)*8, row-major [128][32]
    const int e0 = tid << 3,          r0s = e0 >> 5, c0s = e0 & 31;
    const int e1 = (256 + tid) << 3,  r1s = e1 >> 5, c1s = e1 & 31;
    const u16* gA0 = A + (size_t)(row0 + r0s)*lda + c0s;
    const u16* gA1 = A + (size_t)(row0 + r1s)*lda + c1s;
    const u16* gB0 = W + (size_t)(col0 + r0s)*ldw + c0s;
    const u16* gB1 = W + (size_t)(col0 + r1s)*ldw + c1s;
    u16* lA0 = sA + (wid << 9);          // wave-uniform LDS dest, lane*16B implicit
    u16* lA1 = sA + 2048 + (wid << 9);
    u16* lB0 = sB + (wid << 9);
    u16* lB1 = sB + 2048 + (wid << 9);

    const int la = lane & 15;
    const int lk = (lane >> 4) << 3;
    const u16* rA = sA + (((wr << 6) + la) << 5) + lk;
    const u16* rB = sB + (((wc << 6) + la) << 5) + lk;

    f32x4 acc[4][4];
    #pragma unroll
    for (int m=0;m<4;m++)
        #pragma unroll
        for (int n=0;n<4;n++) acc[m][n] = (f32x4){0.f,0.f,0.f,0.f};

    for (int k0 = 0; k0 < K; k0 += 32){
        gload16(gA0 + k0, lA0);
        gload16(gA1 + k0, lA1);
        gload16(gB0 + k0, lB0);
        gload16(gB1 + k0, lB1);
        __syncthreads();                  // drains vmcnt before barrier (compiler-emitted)
        bf16x8 af[4], bf[4];
        #pragma unroll
        for (int m=0;m<4;m++) af[m] = *reinterpret_cast<const bf16x8*>(rA + (m << 9));
        #pragma unroll
        for (int n=0;n<4;n++) bf[n] = *reinterpret_cast<const bf16x8*>(rB + (n << 9));
        #pragma unroll
        for (int m=0;m<4;m++)
            #pragma unroll
            for (int n=0;n<4;n++)
                acc[m][n] = __builtin_amdgcn_mfma_f32_16x16x32_bf16(af[m], bf[n], acc[m][n], 0, 0, 0);
        __syncthreads();                  // all reads done before next stage overwrites
    }

    // epilogue: D mapping col=lane&15, row=(lane>>4)*4+reg
    const int cr = (lane >> 4) << 2;
    float bb[4];
    #pragma unroll
    for (int n=0;n<4;n++) bb[n] = bias[col0 + (wc << 6) + (n << 4) + la];
    #pragma unroll
    for (int m=0;m<4;m++){
        const int grow = row0 + (wr << 6) + (m << 4) + cr;
        #pragma unroll
        for (int n=0;n<4;n++){
            const int gcol = col0 + (wc << 6) + (n << 4) + la;
            f32x4 v = acc[m][n];
            #pragma unroll
            for (int j=0;j<4;j++){
                float x = v[j] + bb[n];
                if (ACT == 1) x = gelu_f(x);
                C[(size_t)(grow + j)*ldc + gcol] = f2bf(x);
            }
        }
    }
}

// ---------------- attention (N=4 keys, H=4 heads, DH=64) ----------------
__global__ __launch_bounds__(256) void attn_kernel(
    const u16* __restrict__ q, const u16* __restrict__ k, const u16* __restrict__ v,
    u16* __restrict__ ctx)
{
    __shared__ float sQ[256], sK[1024], sV[1024], sS[16], sA[16];
    const int b = blockIdx.x, t = threadIdx.x;
    sQ[t] = bf2f(q[(size_t)b*256 + t]);
    #pragma unroll
    for (int n=0;n<4;n++){
        sK[n*256+t] = bf2f(k[(size_t)b*1024 + n*256 + t]);
        sV[n*256+t] = bf2f(v[(size_t)b*1024 + n*256 + t]);
    }
    __syncthreads();
    if (t < 16){
        int h = t>>2, n = t&3;
        float s = 0.f;
        const int o = h*64;
        #pragma unroll
        for (int dh=0; dh<64; ++dh) s += sQ[o+dh]*sK[n*256+o+dh];
        sS[t] = s * 0.125f;   // 1/sqrt(64)
    }
    __syncthreads();
    if (t < 4){
        float a0=sS[t*4+0], a1=sS[t*4+1], a2=sS[t*4+2], a3=sS[t*4+3];
        float m = fmaxf(fmaxf(a0,a1), fmaxf(a2,a3));
        float e0=expf(a0-m), e1=expf(a1-m), e2=expf(a2-m), e3=expf(a3-m);
        float inv = 1.0f/(e0+e1+e2+e3);
        sA[t*4+0]=e0*inv; sA[t*4+1]=e1*inv; sA[t*4+2]=e2*inv; sA[t*4+3]=e3*inv;
    }
    __syncthreads();
    const int h = t>>6;
    float c = sA[h*4+0]*sV[t] + sA[h*4+1]*sV[256+t] + sA[h*4+2]*sV[512+t] + sA[h*4+3]*sV[768+t];
    ctx[(size_t)b*256 + t] = f2bf(c);
}

// ---------------- entry = FiLM(LN(query + attn_out)), overwrites wcat[b][0] ----------------
__global__ __launch_bounds__(256) void lnfilm_kernel(
    u16* __restrict__ wcat, const u16* __restrict__ ao, const float* __restrict__ regime,
    const float* __restrict__ sgw, const float* __restrict__ sgb,
    const float* __restrict__ sbw, const float* __restrict__ sbb,
    const float* __restrict__ g1, const float* __restrict__ b1)
{
    const int b = blockIdx.x, t = threadIdx.x;
    float x = bf2f(wcat[(size_t)b*1024 + t]) + bf2f(ao[(size_t)b*256 + t]);
    float s = x, q = x*x;
    #pragma unroll
    for (int o=32;o;o>>=1){ s += __shfl_xor(s,o); q += __shfl_xor(q,o); }
    __shared__ float rs[4], rq[4];
    if ((t&63)==0){ rs[t>>6]=s; rq[t>>6]=q; }
    __syncthreads();
    s = rs[0]+rs[1]+rs[2]+rs[3];
    q = rq[0]+rq[1]+rq[2]+rq[3];
    float mu  = s*(1.0f/256.0f);
    float var = q*(1.0f/256.0f) - mu*mu;
    float rstd = rsqrtf(var + 1e-5f);
    float r0=regime[b*4+0], r1=regime[b*4+1], r2=regime[b*4+2], r3=regime[b*4+3];
    float gam = r0*sgw[t*4+0]+r1*sgw[t*4+1]+r2*sgw[t*4+2]+r3*sgw[t*4+3]+sgb[t];
    float bet = r0*sbw[t*4+0]+r1*sbw[t*4+1]+r2*sbw[t*4+2]+r3*sbw[t*4+3]+sbb[t];
    float e = ((x-mu)*rstd*g1[t]+b1[t])*(1.0f+gam)+bet;
    wcat[(size_t)b*1024 + t] = f2bf(e);
}

// ---------------- fused = LN(t1) -> f32 out ----------------
__global__ __launch_bounds__(256) void ln2_kernel(
    const u16* __restrict__ t1, const float* __restrict__ g, const float* __restrict__ bt,
    float* __restrict__ out)
{
    const int b = blockIdx.x, t = threadIdx.x;
    float x0 = bf2f(t1[(size_t)b*512 + t]);
    float x1 = bf2f(t1[(size_t)b*512 + 256 + t]);
    float s = x0+x1, q = x0*x0 + x1*x1;
    #pragma unroll
    for (int o=32;o;o>>=1){ s += __shfl_xor(s,o); q += __shfl_xor(q,o); }
    __shared__ float rs[4], rq[4];
    if ((t&63)==0){ rs[t>>6]=s; rq[t>>6]=q; }
    __syncthreads();
    s = rs[0]+rs[1]+rs[2]+rs[3];
    q = rq[0]+rq[1]+rq[2]+rq[3];
    float mu  = s*(1.0f/512.0f);
    float var = q*(1.0f/512.0f) - mu*mu;
    float rstd = rsqrtf(var + 1e-5f);
    out[(size_t)b*512 + t]       = (x0-mu)*rstd*g[t]     + bt[t];
    out[(size_t)b*512 + 256 + t] = (x1-mu)*rstd*g[256+t] + bt[256+t];
}

// ---------------- alignment = sigmoid(a @ a2_w^T + a2_b) ----------------
__global__ __launch_bounds__(64) void a2_kernel(
    const u16* __restrict__ a, const float* __restrict__ a2w, const float* __restrict__ a2b,
    float* __restrict__ out)
{
    const int b = blockIdx.x, t = threadIdx.x;
    float s = bf2f(a[(size_t)b*128 + t])*a2w[t] + bf2f(a[(size_t)b*128 + 64 + t])*a2w[64+t];
    #pragma unroll
    for (int o=32;o;o>>=1) s += __shfl_xor(s,o);
    if (t==0) out[b] = 1.0f/(1.0f+expf(-(s + a2b[0])));
}

extern "C" void kernel_launch(void* const* d_in, const int* in_sizes, int n_in,
                              void* d_out, int out_size, void* d_ws, size_t ws_size,
                              hipStream_t stream) {
    const float* w0   = (const float*)d_in[0];
    const float* w1   = (const float*)d_in[1];
    const float* w2   = (const float*)d_in[2];
    const float* w3   = (const float*)d_in[3];
    const float* regime = (const float*)d_in[4];
    const float* tfw  = (const float*)d_in[5];
    const float* in_proj_w = (const float*)d_in[6];
    const float* in_proj_b = (const float*)d_in[7];
    const float* out_proj_w = (const float*)d_in[8];
    const float* out_proj_b = (const float*)d_in[9];
    const float* ln1_g = (const float*)d_in[10];
    const float* ln1_b = (const float*)d_in[11];
    const float* sg_w = (const float*)d_in[12];
    const float* sg_b = (const float*)d_in[13];
    const float* sb_w = (const float*)d_in[14];
    const float* sb_b = (const float*)d_in[15];
    const float* f1_w = (const float*)d_in[16];
    const float* f1_b = (const float*)d_in[17];
    const float* f2_w = (const float*)d_in[18];
    const float* f2_b = (const float*)d_in[19];
    const float* ln2_g = (const float*)d_in[20];
    const float* ln2_b = (const float*)d_in[21];
    const float* a1_w = (const float*)d_in[22];
    const float* a1_b = (const float*)d_in[23];
    const float* a2_w = (const float*)d_in[24];
    const float* a2_b = (const float*)d_in[25];

    char* ws = (char*)d_ws;
    // layout (bytes): wcat 64MiB | q/ctx 16MiB | k 64MiB | v 64MiB | ao 16MiB  => 224 MiB total
    u16* wcat  = (u16*)(ws);
    u16* qbuf  = (u16*)(ws + 67108864ull);
    u16* kbuf  = (u16*)(ws + 83886080ull);
    u16* vbuf  = (u16*)(ws + 150994944ull);
    u16* aobuf = (u16*)(ws + 218103808ull);
    // aliases:
    u16* hbuf  = kbuf;    // B x 1024 bf16 (after attn)
    u16* t1buf = vbuf;    // B x 512  bf16 (after attn)
    u16* abuf  = aobuf;   // B x 128  bf16 (after ao consumed)
    // bf16 weights:
    u16* ipw   = aobuf;                        // in_proj bf16 (384 KiB) - dead before ao written
    u16* wbf   = (u16*)(ws + 184549376ull);    // vbuf + 32MiB, free after attn (t1 uses first 32MiB)
    u16* opw   = wbf;                // 65536
    u16* f1w   = wbf + 65536;        // 1048576
    u16* f2w   = wbf + 1114112;      // 524288
    u16* a1w   = wbf + 1638400;      // 131072

    float* out_fused = (float*)d_out;
    float* out_align = (float*)d_out + (size_t)NB*512;

    // 1. weighted (scaled) -> wcat ; in_proj -> bf16
    prep_kernel<<<NB*64/256, 256, 0, stream>>>(w0,w1,w2,w3,tfw,wcat);
    conv1_kernel<<<192, 256, 0, stream>>>(in_proj_w, ipw);
    // 2. q = query @ wq^T + bq
    mgemm_kernel<0><<<dim3(256, 2), 256, 0, stream>>>(wcat, 1024, ipw,        256, in_proj_b,     qbuf, 256, 256);
    // 3. k = weighted @ wk^T + bk   (M = 4B rows)
    mgemm_kernel<0><<<dim3(1024, 2), 256, 0, stream>>>(wcat, 256, ipw+65536,  256, in_proj_b+256, kbuf, 256, 256);
    // 4. v = weighted @ wv^T + bv
    mgemm_kernel<0><<<dim3(1024, 2), 256, 0, stream>>>(wcat, 256, ipw+131072, 256, in_proj_b+512, vbuf, 256, 256);
    // 5. attention -> ctx (overwrites qbuf)
    attn_kernel<<<NB, 256, 0, stream>>>(qbuf, kbuf, vbuf, qbuf);
    // 5b. remaining weights -> bf16 (into dead v-tail region)
    conv2_kernel<<<1728, 256, 0, stream>>>(out_proj_w, opw, f1_w, f1w, f2_w, f2w, a1_w, a1w);
    // 6. attn_out = ctx @ out_proj^T + b
    mgemm_kernel<0><<<dim3(256, 2), 256, 0, stream>>>(qbuf, 256, opw, 256, out_proj_b, aobuf, 256, 256);
    // 7. entry = FiLM(LN(query+attn_out)) -> wcat[:,0:256]  (wcat becomes `cat`)
    lnfilm_kernel<<<NB, 256, 0, stream>>>(wcat, aobuf, regime, sg_w, sg_b, sb_w, sb_b, ln1_g, ln1_b);
    // 8. h = gelu(cat @ f1^T + b) -> hbuf
    mgemm_kernel<1><<<dim3(256, 8), 256, 0, stream>>>(wcat, 1024, f1w, 1024, f1_b, hbuf, 1024, 1024);
    // 9. t1 = h @ f2^T + b
    mgemm_kernel<0><<<dim3(256, 4), 256, 0, stream>>>(hbuf, 1024, f2w, 1024, f2_b, t1buf, 512, 1024);
    // 10. fused = LN(t1) -> out
    ln2_kernel<<<NB, 256, 0, stream>>>(t1buf, ln2_g, ln2_b, out_fused);
    // 11. a = gelu(cat @ a1^T + b)
    mgemm_kernel<1><<<dim3(256, 1), 256, 0, stream>>>(wcat, 1024, a1w, 1024, a1_b, abuf, 128, 1024);
    // 12. alignment = sigmoid(a @ a2^T + b)
    a2_kernel<<<NB, 64, 0, stream>>>(abuf, a2_w, a2_b, out_align);
}

// Round 4
// 430.471 us; speedup vs baseline: 4.9841x; 1.0045x over previous
//
#include <hip/hip_runtime.h>
#include <math.h>

#define NB 32768   // batch
// D=256, N=4, OUT=512, H=4, DH=64

typedef unsigned short u16;
typedef __attribute__((ext_vector_type(4))) float f32x4;
typedef __attribute__((ext_vector_type(8))) short bf16x8;

__device__ __forceinline__ float bf2f(u16 u){ return __uint_as_float(((unsigned int)u)<<16); }
__device__ __forceinline__ u16 f2bf(float f){
    unsigned int x = __float_as_uint(f);
    x += 0x7fffu + ((x>>16)&1u);   // round-to-nearest-even
    return (u16)(x>>16);
}
// gelu exact-erf via A&S 7.1.26 (|eps|<=1.5e-7), branchless: rcp + exp + 5 fma
__device__ __forceinline__ float gelu_f(float x){
    float z = fabsf(x) * 0.70710678118654752f;
    float t = __builtin_amdgcn_rcpf(1.0f + 0.3275911f*z);
    float p = t*(0.254829592f + t*(-0.284496736f + t*(1.421413741f + t*(-1.453152027f + t*1.061405429f))));
    float e = __expf(-z*z);
    float erf_abs = 1.0f - p*e;
    float erfv = copysignf(erf_abs, x);
    return 0.5f*x*(1.0f + erfv);
}

__device__ __forceinline__ void gload16(const void* g, void* l){
    __builtin_amdgcn_global_load_lds(
        (const __attribute__((address_space(1))) unsigned int*)g,
        (__attribute__((address_space(3))) unsigned int*)l, 16, 0, 0);
}

// ---------------- prep: wcat[b][n][d] = w_n[b][d] * softmax(tfw)[n]  (bf16) ----------------
__global__ __launch_bounds__(256) void prep_kernel(
    const float* __restrict__ w0, const float* __restrict__ w1,
    const float* __restrict__ w2, const float* __restrict__ w3,
    const float* __restrict__ tfw, u16* __restrict__ wcat)
{
    float t0=tfw[0], t1=tfw[1], t2=tfw[2], t3=tfw[3];
    float m = fmaxf(fmaxf(t0,t1), fmaxf(t2,t3));
    float e0=expf(t0-m), e1=expf(t1-m), e2=expf(t2-m), e3=expf(t3-m);
    float inv = 1.0f/(e0+e1+e2+e3);
    float s0=e0*inv, s1=e1*inv, s2=e2*inv, s3=e3*inv;

    int idx = blockIdx.x*256 + threadIdx.x;      // B*64 threads, 4 d's each
    int b  = idx >> 6;
    int d4 = (idx & 63) << 2;
    size_t src = (size_t)b*256 + d4;
    float4 a0 = *reinterpret_cast<const float4*>(w0 + src);
    float4 a1 = *reinterpret_cast<const float4*>(w1 + src);
    float4 a2 = *reinterpret_cast<const float4*>(w2 + src);
    float4 a3 = *reinterpret_cast<const float4*>(w3 + src);
    size_t dst = (size_t)b*1024 + d4;
    ushort4 o;
    o.x=f2bf(a0.x*s0); o.y=f2bf(a0.y*s0); o.z=f2bf(a0.z*s0); o.w=f2bf(a0.w*s0);
    *reinterpret_cast<ushort4*>(wcat + dst) = o;
    o.x=f2bf(a1.x*s1); o.y=f2bf(a1.y*s1); o.z=f2bf(a1.z*s1); o.w=f2bf(a1.w*s1);
    *reinterpret_cast<ushort4*>(wcat + dst + 256) = o;
    o.x=f2bf(a2.x*s2); o.y=f2bf(a2.y*s2); o.z=f2bf(a2.z*s2); o.w=f2bf(a2.w*s2);
    *reinterpret_cast<ushort4*>(wcat + dst + 512) = o;
    o.x=f2bf(a3.x*s3); o.y=f2bf(a3.y*s3); o.z=f2bf(a3.z*s3); o.w=f2bf(a3.w*s3);
    *reinterpret_cast<ushort4*>(wcat + dst + 768) = o;
}

// ---------------- weight fp32 -> bf16 conversion ----------------
__global__ __launch_bounds__(256) void conv1_kernel(const float* __restrict__ s, u16* __restrict__ d){
    int i = blockIdx.x*256 + threadIdx.x;
    float4 v = reinterpret_cast<const float4*>(s)[i];
    ushort4 o; o.x=f2bf(v.x); o.y=f2bf(v.y); o.z=f2bf(v.z); o.w=f2bf(v.w);
    reinterpret_cast<ushort4*>(d)[i] = o;
}

__global__ __launch_bounds__(256) void conv2_kernel(
    const float* __restrict__ s0, u16* __restrict__ d0,   // out_proj 16384 chunks
    const float* __restrict__ s1, u16* __restrict__ d1,   // f1       262144
    const float* __restrict__ s2, u16* __restrict__ d2,   // f2       131072
    const float* __restrict__ s3, u16* __restrict__ d3)   // a1       32768
{
    int i = blockIdx.x*256 + threadIdx.x;
    const float* s; u16* d; int off;
    if      (i < 16384) { s=s0; d=d0; off=i; }
    else if (i < 278528){ s=s1; d=d1; off=i-16384; }
    else if (i < 409600){ s=s2; d=d2; off=i-278528; }
    else                { s=s3; d=d3; off=i-409600; }
    float4 v = reinterpret_cast<const float4*>(s)[off];
    ushort4 o; o.x=f2bf(v.x); o.y=f2bf(v.y); o.z=f2bf(v.z); o.w=f2bf(v.w);
    reinterpret_cast<ushort4*>(d)[off] = o;
}

// ---------------- MFMA GEMM: C[M,N] = act(A[M,K] @ W[N,K]^T + bias), all bf16, fp32 acc ----------------
// 128x128 tile, BK=32, 256 threads = 4 waves, wave quadrant 64x64, 4x4 fragments of 16x16x32.
// Swapped-operand mfma: acc reg-dim = C columns -> vectorized ushort4 C-stores; bias folded into acc init.
template<int ACT>   // 0 = none, 1 = exact gelu
__global__ __launch_bounds__(256) void mgemm_kernel(
    const u16* __restrict__ A, int lda,
    const u16* __restrict__ W, int ldw,
    const float* __restrict__ bias,
    u16* __restrict__ C, int ldc, int K)
{
    __shared__ __align__(16) u16 sA[4096];   // [128][32]
    __shared__ __align__(16) u16 sB[4096];   // [128][32]

    const int tid  = threadIdx.x;
    const int lane = tid & 63;
    const int wid  = tid >> 6;
    const int wr   = wid >> 1, wc = wid & 1;
    const int row0 = blockIdx.x << 7, col0 = blockIdx.y << 7;

    // staging: issue i covers tile elements e = (i*256 + tid)*8, row-major [128][32]
    const int e0 = tid << 3,          r0s = e0 >> 5, c0s = e0 & 31;
    const int e1 = (256 + tid) << 3,  r1s = e1 >> 5, c1s = e1 & 31;
    const u16* gA0 = A + (size_t)(row0 + r0s)*lda + c0s;
    const u16* gA1 = A + (size_t)(row0 + r1s)*lda + c1s;
    const u16* gB0 = W + (size_t)(col0 + r0s)*ldw + c0s;
    const u16* gB1 = W + (size_t)(col0 + r1s)*ldw + c1s;
    u16* lA0 = sA + (wid << 9);          // wave-uniform LDS dest, lane*16B implicit
    u16* lA1 = sA + 2048 + (wid << 9);
    u16* lB0 = sB + (wid << 9);
    u16* lB1 = sB + 2048 + (wid << 9);

    const int la  = lane & 15;
    const int lk  = (lane >> 4) << 3;
    const int hi4 = (lane >> 4) << 2;
    const u16* rA = sA + (((wr << 6) + la) << 5) + lk;
    const u16* rB = sB + (((wc << 6) + la) << 5) + lk;

    // acc[m][n] reg j = C[row0+wr*64+m*16+la][col0+wc*64+n*16+hi4+j]; init = bias (same for all m)
    f32x4 acc[4][4];
    {
        f32x4 binit[4];
        #pragma unroll
        for (int n=0;n<4;n++){
            float4 b4 = *reinterpret_cast<const float4*>(bias + col0 + (wc<<6) + (n<<4) + hi4);
            binit[n] = (f32x4){b4.x, b4.y, b4.z, b4.w};
        }
        #pragma unroll
        for (int m=0;m<4;m++)
            #pragma unroll
            for (int n=0;n<4;n++) acc[m][n] = binit[n];
    }

    for (int k0 = 0; k0 < K; k0 += 32){
        gload16(gA0 + k0, lA0);
        gload16(gA1 + k0, lA1);
        gload16(gB0 + k0, lB0);
        gload16(gB1 + k0, lB1);
        __syncthreads();
        bf16x8 af[4], bf[4];
        #pragma unroll
        for (int m=0;m<4;m++) af[m] = *reinterpret_cast<const bf16x8*>(rA + (m << 9));
        #pragma unroll
        for (int n=0;n<4;n++) bf[n] = *reinterpret_cast<const bf16x8*>(rB + (n << 9));
        #pragma unroll
        for (int m=0;m<4;m++)
            #pragma unroll
            for (int n=0;n<4;n++)   // swapped operands: reg-dim = W-rows = C-cols
                acc[m][n] = __builtin_amdgcn_mfma_f32_16x16x32_bf16(bf[n], af[m], acc[m][n], 0, 0, 0);
        __syncthreads();
    }

    // epilogue: 16 x ushort4 stores per thread
    #pragma unroll
    for (int m=0;m<4;m++){
        const int grow = row0 + (wr << 6) + (m << 4) + la;
        u16* crow = C + (size_t)grow*ldc + col0 + (wc << 6) + hi4;
        #pragma unroll
        for (int n=0;n<4;n++){
            f32x4 v = acc[m][n];
            float x0=v[0], x1=v[1], x2=v[2], x3=v[3];
            if (ACT == 1){ x0=gelu_f(x0); x1=gelu_f(x1); x2=gelu_f(x2); x3=gelu_f(x3); }
            ushort4 o; o.x=f2bf(x0); o.y=f2bf(x1); o.z=f2bf(x2); o.w=f2bf(x3);
            *reinterpret_cast<ushort4*>(crow + (n << 4)) = o;
        }
    }
}

// ---------------- attention (N=4 keys, H=4 heads, DH=64), merged kv layout [b][n][k|v] ----------------
__global__ __launch_bounds__(256) void attn_kernel(
    const u16* __restrict__ q, const u16* __restrict__ kv,
    u16* __restrict__ ctx)
{
    __shared__ float sQ[256], sK[1024], sV[1024], sS[16], sA[16];
    const int b = blockIdx.x, t = threadIdx.x;
    sQ[t] = bf2f(q[(size_t)b*256 + t]);
    #pragma unroll
    for (int n=0;n<4;n++){
        sK[n*256+t] = bf2f(kv[(size_t)b*2048 + n*512 + t]);
        sV[n*256+t] = bf2f(kv[(size_t)b*2048 + n*512 + 256 + t]);
    }
    __syncthreads();
    if (t < 16){
        int h = t>>2, n = t&3;
        float s = 0.f;
        const int o = h*64;
        #pragma unroll
        for (int dh=0; dh<64; ++dh) s += sQ[o+dh]*sK[n*256+o+dh];
        sS[t] = s * 0.125f;   // 1/sqrt(64)
    }
    __syncthreads();
    if (t < 4){
        float a0=sS[t*4+0], a1=sS[t*4+1], a2=sS[t*4+2], a3=sS[t*4+3];
        float m = fmaxf(fmaxf(a0,a1), fmaxf(a2,a3));
        float e0=expf(a0-m), e1=expf(a1-m), e2=expf(a2-m), e3=expf(a3-m);
        float inv = 1.0f/(e0+e1+e2+e3);
        sA[t*4+0]=e0*inv; sA[t*4+1]=e1*inv; sA[t*4+2]=e2*inv; sA[t*4+3]=e3*inv;
    }
    __syncthreads();
    const int h = t>>6;
    float c = sA[h*4+0]*sV[t] + sA[h*4+1]*sV[256+t] + sA[h*4+2]*sV[512+t] + sA[h*4+3]*sV[768+t];
    ctx[(size_t)b*256 + t] = f2bf(c);
}

// ---------------- entry = FiLM(LN(query + attn_out)), overwrites wcat[b][0] ----------------
__global__ __launch_bounds__(256) void lnfilm_kernel(
    u16* __restrict__ wcat, const u16* __restrict__ ao, const float* __restrict__ regime,
    const float* __restrict__ sgw, const float* __restrict__ sgb,
    const float* __restrict__ sbw, const float* __restrict__ sbb,
    const float* __restrict__ g1, const float* __restrict__ b1)
{
    const int b = blockIdx.x, t = threadIdx.x;
    float x = bf2f(wcat[(size_t)b*1024 + t]) + bf2f(ao[(size_t)b*256 + t]);
    float s = x, q = x*x;
    #pragma unroll
    for (int o=32;o;o>>=1){ s += __shfl_xor(s,o); q += __shfl_xor(q,o); }
    __shared__ float rs[4], rq[4];
    if ((t&63)==0){ rs[t>>6]=s; rq[t>>6]=q; }
    __syncthreads();
    s = rs[0]+rs[1]+rs[2]+rs[3];
    q = rq[0]+rq[1]+rq[2]+rq[3];
    float mu  = s*(1.0f/256.0f);
    float var = q*(1.0f/256.0f) - mu*mu;
    float rstd = rsqrtf(var + 1e-5f);
    float r0=regime[b*4+0], r1=regime[b*4+1], r2=regime[b*4+2], r3=regime[b*4+3];
    float gam = r0*sgw[t*4+0]+r1*sgw[t*4+1]+r2*sgw[t*4+2]+r3*sgw[t*4+3]+sgb[t];
    float bet = r0*sbw[t*4+0]+r1*sbw[t*4+1]+r2*sbw[t*4+2]+r3*sbw[t*4+3]+sbb[t];
    float e = ((x-mu)*rstd*g1[t]+b1[t])*(1.0f+gam)+bet;
    wcat[(size_t)b*1024 + t] = f2bf(e);
}

// ---------------- fused = LN(t1) -> f32 out ----------------
__global__ __launch_bounds__(256) void ln2_kernel(
    const u16* __restrict__ t1, const float* __restrict__ g, const float* __restrict__ bt,
    float* __restrict__ out)
{
    const int b = blockIdx.x, t = threadIdx.x;
    float x0 = bf2f(t1[(size_t)b*512 + t]);
    float x1 = bf2f(t1[(size_t)b*512 + 256 + t]);
    float s = x0+x1, q = x0*x0 + x1*x1;
    #pragma unroll
    for (int o=32;o;o>>=1){ s += __shfl_xor(s,o); q += __shfl_xor(q,o); }
    __shared__ float rs[4], rq[4];
    if ((t&63)==0){ rs[t>>6]=s; rq[t>>6]=q; }
    __syncthreads();
    s = rs[0]+rs[1]+rs[2]+rs[3];
    q = rq[0]+rq[1]+rq[2]+rq[3];
    float mu  = s*(1.0f/512.0f);
    float var = q*(1.0f/512.0f) - mu*mu;
    float rstd = rsqrtf(var + 1e-5f);
    out[(size_t)b*512 + t]       = (x0-mu)*rstd*g[t]     + bt[t];
    out[(size_t)b*512 + 256 + t] = (x1-mu)*rstd*g[256+t] + bt[256+t];
}

// ---------------- alignment = sigmoid(a @ a2_w^T + a2_b) ----------------
__global__ __launch_bounds__(64) void a2_kernel(
    const u16* __restrict__ a, const float* __restrict__ a2w, const float* __restrict__ a2b,
    float* __restrict__ out)
{
    const int b = blockIdx.x, t = threadIdx.x;
    float s = bf2f(a[(size_t)b*128 + t])*a2w[t] + bf2f(a[(size_t)b*128 + 64 + t])*a2w[64+t];
    #pragma unroll
    for (int o=32;o;o>>=1) s += __shfl_xor(s,o);
    if (t==0) out[b] = 1.0f/(1.0f+expf(-(s + a2b[0])));
}

extern "C" void kernel_launch(void* const* d_in, const int* in_sizes, int n_in,
                              void* d_out, int out_size, void* d_ws, size_t ws_size,
                              hipStream_t stream) {
    const float* w0   = (const float*)d_in[0];
    const float* w1   = (const float*)d_in[1];
    const float* w2   = (const float*)d_in[2];
    const float* w3   = (const float*)d_in[3];
    const float* regime = (const float*)d_in[4];
    const float* tfw  = (const float*)d_in[5];
    const float* in_proj_w = (const float*)d_in[6];
    const float* in_proj_b = (const float*)d_in[7];
    const float* out_proj_w = (const float*)d_in[8];
    const float* out_proj_b = (const float*)d_in[9];
    const float* ln1_g = (const float*)d_in[10];
    const float* ln1_b = (const float*)d_in[11];
    const float* sg_w = (const float*)d_in[12];
    const float* sg_b = (const float*)d_in[13];
    const float* sb_w = (const float*)d_in[14];
    const float* sb_b = (const float*)d_in[15];
    const float* f1_w = (const float*)d_in[16];
    const float* f1_b = (const float*)d_in[17];
    const float* f2_w = (const float*)d_in[18];
    const float* f2_b = (const float*)d_in[19];
    const float* ln2_g = (const float*)d_in[20];
    const float* ln2_b = (const float*)d_in[21];
    const float* a1_w = (const float*)d_in[22];
    const float* a1_b = (const float*)d_in[23];
    const float* a2_w = (const float*)d_in[24];
    const float* a2_b = (const float*)d_in[25];

    char* ws = (char*)d_ws;
    // layout (bytes): wcat 64MiB | q/ctx 16MiB | kv 128MiB | ao 16MiB  => 224 MiB total
    u16* wcat  = (u16*)(ws);
    u16* qbuf  = (u16*)(ws + 67108864ull);
    u16* kvbuf = (u16*)(ws + 83886080ull);     // B x 4 x [k(256)|v(256)]
    u16* aobuf = (u16*)(ws + 218103808ull);
    // aliases:
    u16* hbuf  = kvbuf;                        // B x 1024 bf16 (after attn): 80..144MiB
    u16* t1buf = (u16*)(ws + 150994944ull);    // B x 512  bf16: 144..176MiB
    u16* abuf  = aobuf;                        // B x 128  bf16 (after ao consumed)
    u16* ipw   = aobuf;                        // in_proj bf16 (384 KiB) - dead before ao written
    u16* wbf   = (u16*)(ws + 184549376ull);    // 176MiB.. (dead kv tail after attn)
    u16* opw   = wbf;                // 65536 elems
    u16* f1w   = wbf + 65536;        // 1048576
    u16* f2w   = wbf + 1114112;      // 524288
    u16* a1w   = wbf + 1638400;      // 131072

    float* out_fused = (float*)d_out;
    float* out_align = (float*)d_out + (size_t)NB*512;

    // 1. weighted (scaled) -> wcat ; in_proj -> bf16
    prep_kernel<<<NB*64/256, 256, 0, stream>>>(w0,w1,w2,w3,tfw,wcat);
    conv1_kernel<<<192, 256, 0, stream>>>(in_proj_w, ipw);
    // 2. q = query @ wq^T + bq
    mgemm_kernel<0><<<dim3(256, 2), 256, 0, stream>>>(wcat, 1024, ipw, 256, in_proj_b, qbuf, 256, 256);
    // 3. kv = weighted @ [wk;wv]^T + b  (M = 4B rows, N = 512)
    mgemm_kernel<0><<<dim3(1024, 4), 256, 0, stream>>>(wcat, 256, ipw+65536, 256, in_proj_b+256, kvbuf, 512, 256);
    // 4. attention -> ctx (overwrites qbuf)
    attn_kernel<<<NB, 256, 0, stream>>>(qbuf, kvbuf, qbuf);
    // 4b. remaining weights -> bf16 (into dead kv-tail region)
    conv2_kernel<<<1728, 256, 0, stream>>>(out_proj_w, opw, f1_w, f1w, f2_w, f2w, a1_w, a1w);
    // 5. attn_out = ctx @ out_proj^T + b
    mgemm_kernel<0><<<dim3(256, 2), 256, 0, stream>>>(qbuf, 256, opw, 256, out_proj_b, aobuf, 256, 256);
    // 6. entry = FiLM(LN(query+attn_out)) -> wcat[:,0:256]  (wcat becomes `cat`)
    lnfilm_kernel<<<NB, 256, 0, stream>>>(wcat, aobuf, regime, sg_w, sg_b, sb_w, sb_b, ln1_g, ln1_b);
    // 7. h = gelu(cat @ f1^T + b) -> hbuf
    mgemm_kernel<1><<<dim3(256, 8), 256, 0, stream>>>(wcat, 1024, f1w, 1024, f1_b, hbuf, 1024, 1024);
    // 8. t1 = h @ f2^T + b
    mgemm_kernel<0><<<dim3(256, 4), 256, 0, stream>>>(hbuf, 1024, f2w, 1024, f2_b, t1buf, 512, 1024);
    // 9. fused = LN(t1) -> out
    ln2_kernel<<<NB, 256, 0, stream>>>(t1buf, ln2_g, ln2_b, out_fused);
    // 10. a = gelu(cat @ a1^T + b)
    mgemm_kernel<1><<<dim3(256, 1), 256, 0, stream>>>(wcat, 1024, a1w, 1024, a1_b, abuf, 128, 1024);
    // 11. alignment = sigmoid(a @ a2^T + b)
    a2_kernel<<<NB, 64, 0, stream>>>(abuf, a2_w, a2_b, out_align);
}

// Round 5
// 384.505 us; speedup vs baseline: 5.5799x; 1.1195x over previous
//
#include <hip/hip_runtime.h>
#include <math.h>

#define NB 32768   // batch
// D=256, N=4, OUT=512, H=4, DH=64

typedef unsigned short u16;
typedef __attribute__((ext_vector_type(4))) float f32x4;
typedef __attribute__((ext_vector_type(8))) short bf16x8;

__device__ __forceinline__ float bf2f(u16 u){ return __uint_as_float(((unsigned int)u)<<16); }
__device__ __forceinline__ u16 f2bf(float f){
    unsigned int x = __float_as_uint(f);
    x += 0x7fffu + ((x>>16)&1u);   // round-to-nearest-even
    return (u16)(x>>16);
}
// gelu exact-erf via A&S 7.1.26 (|eps|<=1.5e-7), branchless: rcp + exp + 5 fma
__device__ __forceinline__ float gelu_f(float x){
    float z = fabsf(x) * 0.70710678118654752f;
    float t = __builtin_amdgcn_rcpf(1.0f + 0.3275911f*z);
    float p = t*(0.254829592f + t*(-0.284496736f + t*(1.421413741f + t*(-1.453152027f + t*1.061405429f))));
    float e = __expf(-z*z);
    float erf_abs = 1.0f - p*e;
    float erfv = copysignf(erf_abs, x);
    return 0.5f*x*(1.0f + erfv);
}

__device__ __forceinline__ void gload16(const void* g, void* l){
    __builtin_amdgcn_global_load_lds(
        (const __attribute__((address_space(1))) unsigned int*)g,
        (__attribute__((address_space(3))) unsigned int*)l, 16, 0, 0);
}

// ---------------- prep: wcat[b][n][d] = w_n[b][d] * softmax(tfw)[n]  (bf16) ----------------
__global__ __launch_bounds__(256) void prep_kernel(
    const float* __restrict__ w0, const float* __restrict__ w1,
    const float* __restrict__ w2, const float* __restrict__ w3,
    const float* __restrict__ tfw, u16* __restrict__ wcat)
{
    float t0=tfw[0], t1=tfw[1], t2=tfw[2], t3=tfw[3];
    float m = fmaxf(fmaxf(t0,t1), fmaxf(t2,t3));
    float e0=expf(t0-m), e1=expf(t1-m), e2=expf(t2-m), e3=expf(t3-m);
    float inv = 1.0f/(e0+e1+e2+e3);
    float s0=e0*inv, s1=e1*inv, s2=e2*inv, s3=e3*inv;

    int idx = blockIdx.x*256 + threadIdx.x;      // B*64 threads, 4 d's each
    int b  = idx >> 6;
    int d4 = (idx & 63) << 2;
    size_t src = (size_t)b*256 + d4;
    float4 a0 = *reinterpret_cast<const float4*>(w0 + src);
    float4 a1 = *reinterpret_cast<const float4*>(w1 + src);
    float4 a2 = *reinterpret_cast<const float4*>(w2 + src);
    float4 a3 = *reinterpret_cast<const float4*>(w3 + src);
    size_t dst = (size_t)b*1024 + d4;
    ushort4 o;
    o.x=f2bf(a0.x*s0); o.y=f2bf(a0.y*s0); o.z=f2bf(a0.z*s0); o.w=f2bf(a0.w*s0);
    *reinterpret_cast<ushort4*>(wcat + dst) = o;
    o.x=f2bf(a1.x*s1); o.y=f2bf(a1.y*s1); o.z=f2bf(a1.z*s1); o.w=f2bf(a1.w*s1);
    *reinterpret_cast<ushort4*>(wcat + dst + 256) = o;
    o.x=f2bf(a2.x*s2); o.y=f2bf(a2.y*s2); o.z=f2bf(a2.z*s2); o.w=f2bf(a2.w*s2);
    *reinterpret_cast<ushort4*>(wcat + dst + 512) = o;
    o.x=f2bf(a3.x*s3); o.y=f2bf(a3.y*s3); o.z=f2bf(a3.z*s3); o.w=f2bf(a3.w*s3);
    *reinterpret_cast<ushort4*>(wcat + dst + 768) = o;
}

// ---------------- weight fp32 -> bf16 conversion ----------------
__global__ __launch_bounds__(256) void conv1_kernel(const float* __restrict__ s, u16* __restrict__ d){
    int i = blockIdx.x*256 + threadIdx.x;
    float4 v = reinterpret_cast<const float4*>(s)[i];
    ushort4 o; o.x=f2bf(v.x); o.y=f2bf(v.y); o.z=f2bf(v.z); o.w=f2bf(v.w);
    reinterpret_cast<ushort4*>(d)[i] = o;
}

__global__ __launch_bounds__(256) void conv2_kernel(
    const float* __restrict__ s0, u16* __restrict__ d0,   // out_proj 16384 chunks
    const float* __restrict__ s1, u16* __restrict__ d1,   // f1       262144
    const float* __restrict__ s2, u16* __restrict__ d2,   // f2       131072
    const float* __restrict__ s3, u16* __restrict__ d3)   // a1       32768
{
    int i = blockIdx.x*256 + threadIdx.x;
    const float* s; u16* d; int off;
    if      (i < 16384) { s=s0; d=d0; off=i; }
    else if (i < 278528){ s=s1; d=d1; off=i-16384; }
    else if (i < 409600){ s=s2; d=d2; off=i-278528; }
    else                { s=s3; d=d3; off=i-409600; }
    float4 v = reinterpret_cast<const float4*>(s)[off];
    ushort4 o; o.x=f2bf(v.x); o.y=f2bf(v.y); o.z=f2bf(v.z); o.w=f2bf(v.w);
    reinterpret_cast<ushort4*>(d)[off] = o;
}

// ---------------- 128x128 MFMA GEMM (kept for N<=256 GEMMs) ----------------
template<int ACT>
__global__ __launch_bounds__(256) void mgemm_kernel(
    const u16* __restrict__ A, int lda,
    const u16* __restrict__ W, int ldw,
    const float* __restrict__ bias,
    u16* __restrict__ C, int ldc, int K)
{
    __shared__ __align__(16) u16 sA[4096];   // [128][32]
    __shared__ __align__(16) u16 sB[4096];   // [128][32]

    const int tid  = threadIdx.x;
    const int lane = tid & 63;
    const int wid  = tid >> 6;
    const int wr   = wid >> 1, wc = wid & 1;
    const int row0 = blockIdx.x << 7, col0 = blockIdx.y << 7;

    const int e0 = tid << 3,          r0s = e0 >> 5, c0s = e0 & 31;
    const int e1 = (256 + tid) << 3,  r1s = e1 >> 5, c1s = e1 & 31;
    const u16* gA0 = A + (size_t)(row0 + r0s)*lda + c0s;
    const u16* gA1 = A + (size_t)(row0 + r1s)*lda + c1s;
    const u16* gB0 = W + (size_t)(col0 + r0s)*ldw + c0s;
    const u16* gB1 = W + (size_t)(col0 + r1s)*ldw + c1s;
    u16* lA0 = sA + (wid << 9);
    u16* lA1 = sA + 2048 + (wid << 9);
    u16* lB0 = sB + (wid << 9);
    u16* lB1 = sB + 2048 + (wid << 9);

    const int la  = lane & 15;
    const int lk  = (lane >> 4) << 3;
    const int hi4 = (lane >> 4) << 2;
    const u16* rA = sA + (((wr << 6) + la) << 5) + lk;
    const u16* rB = sB + (((wc << 6) + la) << 5) + lk;

    f32x4 acc[4][4];
    {
        f32x4 binit[4];
        #pragma unroll
        for (int n=0;n<4;n++){
            float4 b4 = *reinterpret_cast<const float4*>(bias + col0 + (wc<<6) + (n<<4) + hi4);
            binit[n] = (f32x4){b4.x, b4.y, b4.z, b4.w};
        }
        #pragma unroll
        for (int m=0;m<4;m++)
            #pragma unroll
            for (int n=0;n<4;n++) acc[m][n] = binit[n];
    }

    for (int k0 = 0; k0 < K; k0 += 32){
        gload16(gA0 + k0, lA0);
        gload16(gA1 + k0, lA1);
        gload16(gB0 + k0, lB0);
        gload16(gB1 + k0, lB1);
        __syncthreads();
        bf16x8 af[4], bf[4];
        #pragma unroll
        for (int m=0;m<4;m++) af[m] = *reinterpret_cast<const bf16x8*>(rA + (m << 9));
        #pragma unroll
        for (int n=0;n<4;n++) bf[n] = *reinterpret_cast<const bf16x8*>(rB + (n << 9));
        #pragma unroll
        for (int m=0;m<4;m++)
            #pragma unroll
            for (int n=0;n<4;n++)
                acc[m][n] = __builtin_amdgcn_mfma_f32_16x16x32_bf16(bf[n], af[m], acc[m][n], 0, 0, 0);
        __syncthreads();
    }

    #pragma unroll
    for (int m=0;m<4;m++){
        const int grow = row0 + (wr << 6) + (m << 4) + la;
        u16* crow = C + (size_t)grow*ldc + col0 + (wc << 6) + hi4;
        #pragma unroll
        for (int n=0;n<4;n++){
            f32x4 v = acc[m][n];
            float x0=v[0], x1=v[1], x2=v[2], x3=v[3];
            if (ACT == 1){ x0=gelu_f(x0); x1=gelu_f(x1); x2=gelu_f(x2); x3=gelu_f(x3); }
            ushort4 o; o.x=f2bf(x0); o.y=f2bf(x1); o.z=f2bf(x2); o.w=f2bf(x3);
            *reinterpret_cast<ushort4*>(crow + (n << 4)) = o;
        }
    }
}

// ---------------- 256x256 MFMA GEMM, BK=32, 3-deep LDS ring, counted vmcnt, swizzled LDS ----------------
// 512 threads = 8 waves (2 Mx4 N); per-wave out 128x64 (8x4 frags); LDS 3x32KB ring.
// Swizzle: LDS(row, slot) holds global k-block (slot ^ ((row>>1)&3)) -> ds_read 2-way conflicts (free).
// Staged via global_load_lds with inverse-permuted global source (linear LDS dest).
template<int ACT>
__global__ __launch_bounds__(512) void gemm256_kernel(
    const u16* __restrict__ A, int lda,
    const u16* __restrict__ W, int ldw,
    const float* __restrict__ bias,
    u16* __restrict__ C, int ldc, int K)
{
    __shared__ __align__(16) u16 sT[49152];   // 3 ring slots x (A[256][32] | B[256][32])

    const int tid  = threadIdx.x;
    const int lane = tid & 63;
    const int wid  = tid >> 6;            // 0..7
    const int wr   = wid >> 2;            // 0..1  (M half)
    const int wc   = wid & 3;             // 0..3  (N quarter)
    const int row0 = blockIdx.x << 8, col0 = blockIdx.y << 8;

    // ---- staging addresses (2 chunks of A + 2 of B per wave per tile) ----
    // chunk c covers tile rows [16c,16c+16); lane i -> row_local i>>2, phys slot i&3
    // phys slot s holds global k-block s ^ ((row>>1)&3)
    const int rA0 = ((wid<<1)    )*16 + (lane>>2);
    const int rA1 = ((wid<<1) + 1)*16 + (lane>>2);
    const int sw0 = ((lane&3) ^ ((rA0>>1)&3)) << 3;
    const int sw1 = ((lane&3) ^ ((rA1>>1)&3)) << 3;
    const u16* pA0 = A + (size_t)(row0 + rA0)*lda + sw0;
    const u16* pA1 = A + (size_t)(row0 + rA1)*lda + sw1;
    const u16* pB0 = W + (size_t)(col0 + rA0)*ldw + sw0;
    const u16* pB1 = W + (size_t)(col0 + rA1)*ldw + sw1;

    // ---- ds_read addressing ----
    const int la  = lane & 15;
    const int sr  = lane >> 4;                  // desired k-block
    const int swze = (sr ^ ((la>>1)&3)) << 3;   // swizzled element offset in row
    const int hi4 = sr << 2;

    f32x4 acc[8][4];
    {
        f32x4 binit[4];
        #pragma unroll
        for (int n=0;n<4;n++){
            float4 b4 = *reinterpret_cast<const float4*>(bias + col0 + (wc<<6) + (n<<4) + hi4);
            binit[n] = (f32x4){b4.x, b4.y, b4.z, b4.w};
        }
        #pragma unroll
        for (int m=0;m<8;m++)
            #pragma unroll
            for (int n=0;n<4;n++) acc[m][n] = binit[n];
    }

    auto stage = [&](int t){
        const int r = t - (t/3)*3;
        u16* dA = &sT[r*16384 + (wid<<10)];
        const int ko = t << 5;
        gload16(pA0 + ko, dA);
        gload16(pA1 + ko, dA + 512);
        gload16(pB0 + ko, dA + 8192);
        gload16(pB1 + ko, dA + 8192 + 512);
    };

    const int NT = K >> 5;
    stage(0);
    stage(1);

    for (int t = 0; t < NT; ++t){
        if (t + 2 < NT){
            stage(t + 2);
            asm volatile("s_waitcnt vmcnt(8)" ::: "memory");
        } else if (t + 1 < NT){
            asm volatile("s_waitcnt vmcnt(4)" ::: "memory");
        } else {
            asm volatile("s_waitcnt vmcnt(0)" ::: "memory");
        }
        __builtin_amdgcn_s_barrier();
        __builtin_amdgcn_sched_barrier(0);

        const int r = t - (t/3)*3;
        const u16* tb = &sT[r*16384];
        const u16* rA = tb + (((wr<<7) + la) << 5) + swze;
        const u16* rB = tb + 8192 + (((wc<<6) + la) << 5) + swze;

        bf16x8 af[8], bf[4];
        #pragma unroll
        for (int m=0;m<8;m++) af[m] = *reinterpret_cast<const bf16x8*>(rA + (m << 9));
        #pragma unroll
        for (int n=0;n<4;n++) bf[n] = *reinterpret_cast<const bf16x8*>(rB + (n << 9));

        __builtin_amdgcn_s_setprio(1);
        #pragma unroll
        for (int m=0;m<8;m++)
            #pragma unroll
            for (int n=0;n<4;n++)
                acc[m][n] = __builtin_amdgcn_mfma_f32_16x16x32_bf16(bf[n], af[m], acc[m][n], 0, 0, 0);
        __builtin_amdgcn_s_setprio(0);
        __builtin_amdgcn_sched_barrier(0);
        asm volatile("" ::: "memory");
        __builtin_amdgcn_s_barrier();
    }

    // epilogue: vectorized ushort4 stores
    #pragma unroll
    for (int m=0;m<8;m++){
        const int grow = row0 + (wr << 7) + (m << 4) + la;
        u16* crow = C + (size_t)grow*ldc + col0 + (wc << 6) + hi4;
        #pragma unroll
        for (int n=0;n<4;n++){
            f32x4 v = acc[m][n];
            float x0=v[0], x1=v[1], x2=v[2], x3=v[3];
            if (ACT == 1){ x0=gelu_f(x0); x1=gelu_f(x1); x2=gelu_f(x2); x3=gelu_f(x3); }
            ushort4 o; o.x=f2bf(x0); o.y=f2bf(x1); o.z=f2bf(x2); o.w=f2bf(x3);
            *reinterpret_cast<ushort4*>(crow + (n << 4)) = o;
        }
    }
}

// ---------------- attention (N=4 keys, H=4 heads, DH=64), merged kv layout [b][n][k|v] ----------------
__global__ __launch_bounds__(256) void attn_kernel(
    const u16* __restrict__ q, const u16* __restrict__ kv,
    u16* __restrict__ ctx)
{
    __shared__ float sQ[256], sK[1024], sV[1024], sS[16], sA[16];
    const int b = blockIdx.x, t = threadIdx.x;
    sQ[t] = bf2f(q[(size_t)b*256 + t]);
    #pragma unroll
    for (int n=0;n<4;n++){
        sK[n*256+t] = bf2f(kv[(size_t)b*2048 + n*512 + t]);
        sV[n*256+t] = bf2f(kv[(size_t)b*2048 + n*512 + 256 + t]);
    }
    __syncthreads();
    if (t < 16){
        int h = t>>2, n = t&3;
        float s = 0.f;
        const int o = h*64;
        #pragma unroll
        for (int dh=0; dh<64; ++dh) s += sQ[o+dh]*sK[n*256+o+dh];
        sS[t] = s * 0.125f;   // 1/sqrt(64)
    }
    __syncthreads();
    if (t < 4){
        float a0=sS[t*4+0], a1=sS[t*4+1], a2=sS[t*4+2], a3=sS[t*4+3];
        float m = fmaxf(fmaxf(a0,a1), fmaxf(a2,a3));
        float e0=expf(a0-m), e1=expf(a1-m), e2=expf(a2-m), e3=expf(a3-m);
        float inv = 1.0f/(e0+e1+e2+e3);
        sA[t*4+0]=e0*inv; sA[t*4+1]=e1*inv; sA[t*4+2]=e2*inv; sA[t*4+3]=e3*inv;
    }
    __syncthreads();
    const int h = t>>6;
    float c = sA[h*4+0]*sV[t] + sA[h*4+1]*sV[256+t] + sA[h*4+2]*sV[512+t] + sA[h*4+3]*sV[768+t];
    ctx[(size_t)b*256 + t] = f2bf(c);
}

// ---------------- entry = FiLM(LN(query + attn_out)), overwrites wcat[b][0] ----------------
__global__ __launch_bounds__(256) void lnfilm_kernel(
    u16* __restrict__ wcat, const u16* __restrict__ ao, const float* __restrict__ regime,
    const float* __restrict__ sgw, const float* __restrict__ sgb,
    const float* __restrict__ sbw, const float* __restrict__ sbb,
    const float* __restrict__ g1, const float* __restrict__ b1)
{
    const int b = blockIdx.x, t = threadIdx.x;
    float x = bf2f(wcat[(size_t)b*1024 + t]) + bf2f(ao[(size_t)b*256 + t]);
    float s = x, q = x*x;
    #pragma unroll
    for (int o=32;o;o>>=1){ s += __shfl_xor(s,o); q += __shfl_xor(q,o); }
    __shared__ float rs[4], rq[4];
    if ((t&63)==0){ rs[t>>6]=s; rq[t>>6]=q; }
    __syncthreads();
    s = rs[0]+rs[1]+rs[2]+rs[3];
    q = rq[0]+rq[1]+rq[2]+rq[3];
    float mu  = s*(1.0f/256.0f);
    float var = q*(1.0f/256.0f) - mu*mu;
    float rstd = rsqrtf(var + 1e-5f);
    float r0=regime[b*4+0], r1=regime[b*4+1], r2=regime[b*4+2], r3=regime[b*4+3];
    float gam = r0*sgw[t*4+0]+r1*sgw[t*4+1]+r2*sgw[t*4+2]+r3*sgw[t*4+3]+sgb[t];
    float bet = r0*sbw[t*4+0]+r1*sbw[t*4+1]+r2*sbw[t*4+2]+r3*sbw[t*4+3]+sbb[t];
    float e = ((x-mu)*rstd*g1[t]+b1[t])*(1.0f+gam)+bet;
    wcat[(size_t)b*1024 + t] = f2bf(e);
}

// ---------------- fused = LN(t1) -> f32 out ----------------
__global__ __launch_bounds__(256) void ln2_kernel(
    const u16* __restrict__ t1, const float* __restrict__ g, const float* __restrict__ bt,
    float* __restrict__ out)
{
    const int b = blockIdx.x, t = threadIdx.x;
    float x0 = bf2f(t1[(size_t)b*512 + t]);
    float x1 = bf2f(t1[(size_t)b*512 + 256 + t]);
    float s = x0+x1, q = x0*x0 + x1*x1;
    #pragma unroll
    for (int o=32;o;o>>=1){ s += __shfl_xor(s,o); q += __shfl_xor(q,o); }
    __shared__ float rs[4], rq[4];
    if ((t&63)==0){ rs[t>>6]=s; rq[t>>6]=q; }
    __syncthreads();
    s = rs[0]+rs[1]+rs[2]+rs[3];
    q = rq[0]+rq[1]+rq[2]+rq[3];
    float mu  = s*(1.0f/512.0f);
    float var = q*(1.0f/512.0f) - mu*mu;
    float rstd = rsqrtf(var + 1e-5f);
    out[(size_t)b*512 + t]       = (x0-mu)*rstd*g[t]     + bt[t];
    out[(size_t)b*512 + 256 + t] = (x1-mu)*rstd*g[256+t] + bt[256+t];
}

// ---------------- alignment = sigmoid(a @ a2_w^T + a2_b) ----------------
__global__ __launch_bounds__(64) void a2_kernel(
    const u16* __restrict__ a, const float* __restrict__ a2w, const float* __restrict__ a2b,
    float* __restrict__ out)
{
    const int b = blockIdx.x, t = threadIdx.x;
    float s = bf2f(a[(size_t)b*128 + t])*a2w[t] + bf2f(a[(size_t)b*128 + 64 + t])*a2w[64+t];
    #pragma unroll
    for (int o=32;o;o>>=1) s += __shfl_xor(s,o);
    if (t==0) out[b] = 1.0f/(1.0f+expf(-(s + a2b[0])));
}

extern "C" void kernel_launch(void* const* d_in, const int* in_sizes, int n_in,
                              void* d_out, int out_size, void* d_ws, size_t ws_size,
                              hipStream_t stream) {
    const float* w0   = (const float*)d_in[0];
    const float* w1   = (const float*)d_in[1];
    const float* w2   = (const float*)d_in[2];
    const float* w3   = (const float*)d_in[3];
    const float* regime = (const float*)d_in[4];
    const float* tfw  = (const float*)d_in[5];
    const float* in_proj_w = (const float*)d_in[6];
    const float* in_proj_b = (const float*)d_in[7];
    const float* out_proj_w = (const float*)d_in[8];
    const float* out_proj_b = (const float*)d_in[9];
    const float* ln1_g = (const float*)d_in[10];
    const float* ln1_b = (const float*)d_in[11];
    const float* sg_w = (const float*)d_in[12];
    const float* sg_b = (const float*)d_in[13];
    const float* sb_w = (const float*)d_in[14];
    const float* sb_b = (const float*)d_in[15];
    const float* f1_w = (const float*)d_in[16];
    const float* f1_b = (const float*)d_in[17];
    const float* f2_w = (const float*)d_in[18];
    const float* f2_b = (const float*)d_in[19];
    const float* ln2_g = (const float*)d_in[20];
    const float* ln2_b = (const float*)d_in[21];
    const float* a1_w = (const float*)d_in[22];
    const float* a1_b = (const float*)d_in[23];
    const float* a2_w = (const float*)d_in[24];
    const float* a2_b = (const float*)d_in[25];

    char* ws = (char*)d_ws;
    // layout (bytes): wcat 64MiB | q/ctx 16MiB | kv 128MiB | ao 16MiB  => 224 MiB total
    u16* wcat  = (u16*)(ws);
    u16* qbuf  = (u16*)(ws + 67108864ull);
    u16* kvbuf = (u16*)(ws + 83886080ull);     // B x 4 x [k(256)|v(256)]
    u16* aobuf = (u16*)(ws + 218103808ull);
    // aliases:
    u16* hbuf  = kvbuf;                        // B x 1024 bf16 (after attn): 80..144MiB
    u16* t1buf = (u16*)(ws + 150994944ull);    // B x 512  bf16: 144..176MiB
    u16* abuf  = aobuf;                        // B x 128  bf16 (after ao consumed)
    u16* ipw   = aobuf;                        // in_proj bf16 (384 KiB) - dead before ao written
    u16* wbf   = (u16*)(ws + 184549376ull);    // 176MiB.. (dead kv tail after attn)
    u16* opw   = wbf;                // 65536 elems
    u16* f1w   = wbf + 65536;        // 1048576
    u16* f2w   = wbf + 1114112;      // 524288
    u16* a1w   = wbf + 1638400;      // 131072

    float* out_fused = (float*)d_out;
    float* out_align = (float*)d_out + (size_t)NB*512;

    // 1. weighted (scaled) -> wcat ; in_proj -> bf16
    prep_kernel<<<NB*64/256, 256, 0, stream>>>(w0,w1,w2,w3,tfw,wcat);
    conv1_kernel<<<192, 256, 0, stream>>>(in_proj_w, ipw);
    // 2. q = query @ wq^T + bq
    mgemm_kernel<0><<<dim3(256, 2), 256, 0, stream>>>(wcat, 1024, ipw, 256, in_proj_b, qbuf, 256, 256);
    // 3. kv = weighted @ [wk;wv]^T + b  (M = 4B rows, N = 512)
    gemm256_kernel<0><<<dim3(512, 2), 512, 0, stream>>>(wcat, 256, ipw+65536, 256, in_proj_b+256, kvbuf, 512, 256);
    // 4. attention -> ctx (overwrites qbuf)
    attn_kernel<<<NB, 256, 0, stream>>>(qbuf, kvbuf, qbuf);
    // 4b. remaining weights -> bf16 (into dead kv-tail region)
    conv2_kernel<<<1728, 256, 0, stream>>>(out_proj_w, opw, f1_w, f1w, f2_w, f2w, a1_w, a1w);
    // 5. attn_out = ctx @ out_proj^T + b
    mgemm_kernel<0><<<dim3(256, 2), 256, 0, stream>>>(qbuf, 256, opw, 256, out_proj_b, aobuf, 256, 256);
    // 6. entry = FiLM(LN(query+attn_out)) -> wcat[:,0:256]  (wcat becomes `cat`)
    lnfilm_kernel<<<NB, 256, 0, stream>>>(wcat, aobuf, regime, sg_w, sg_b, sb_w, sb_b, ln1_g, ln1_b);
    // 7. h = gelu(cat @ f1^T + b) -> hbuf
    gemm256_kernel<1><<<dim3(128, 4), 512, 0, stream>>>(wcat, 1024, f1w, 1024, f1_b, hbuf, 1024, 1024);
    // 8. t1 = h @ f2^T + b
    gemm256_kernel<0><<<dim3(128, 2), 512, 0, stream>>>(hbuf, 1024, f2w, 1024, f2_b, t1buf, 512, 1024);
    // 9. fused = LN(t1) -> out
    ln2_kernel<<<NB, 256, 0, stream>>>(t1buf, ln2_g, ln2_b, out_fused);
    // 10. a = gelu(cat @ a1^T + b)
    mgemm_kernel<1><<<dim3(256, 1), 256, 0, stream>>>(wcat, 1024, a1w, 1024, a1_b, abuf, 128, 1024);
    // 11. alignment = sigmoid(a @ a2^T + b)
    a2_kernel<<<NB, 64, 0, stream>>>(abuf, a2_w, a2_b, out_align);
}

// Round 6
// 382.026 us; speedup vs baseline: 5.6161x; 1.0065x over previous
//
#include <hip/hip_runtime.h>
#include <math.h>

#define NB 32768   // batch
// D=256, N=4, OUT=512, H=4, DH=64

typedef unsigned short u16;
typedef __attribute__((ext_vector_type(4))) float f32x4;
typedef __attribute__((ext_vector_type(8))) short bf16x8;

__device__ __forceinline__ float bf2f(u16 u){ return __uint_as_float(((unsigned int)u)<<16); }
__device__ __forceinline__ u16 f2bf(float f){
    unsigned int x = __float_as_uint(f);
    x += 0x7fffu + ((x>>16)&1u);   // round-to-nearest-even
    return (u16)(x>>16);
}
// gelu exact-erf via A&S 7.1.26 (|eps|<=1.5e-7), branchless: rcp + exp + 5 fma
__device__ __forceinline__ float gelu_f(float x){
    float z = fabsf(x) * 0.70710678118654752f;
    float t = __builtin_amdgcn_rcpf(1.0f + 0.3275911f*z);
    float p = t*(0.254829592f + t*(-0.284496736f + t*(1.421413741f + t*(-1.453152027f + t*1.061405429f))));
    float e = __expf(-z*z);
    float erf_abs = 1.0f - p*e;
    float erfv = copysignf(erf_abs, x);
    return 0.5f*x*(1.0f + erfv);
}

__device__ __forceinline__ void gload16(const void* g, void* l){
    __builtin_amdgcn_global_load_lds(
        (const __attribute__((address_space(1))) unsigned int*)g,
        (__attribute__((address_space(3))) unsigned int*)l, 16, 0, 0);
}

// ---------------- prep: wcat[b][n][d] = w_n[b][d] * softmax(tfw)[n]  (bf16) ----------------
__global__ __launch_bounds__(256) void prep_kernel(
    const float* __restrict__ w0, const float* __restrict__ w1,
    const float* __restrict__ w2, const float* __restrict__ w3,
    const float* __restrict__ tfw, u16* __restrict__ wcat)
{
    float t0=tfw[0], t1=tfw[1], t2=tfw[2], t3=tfw[3];
    float m = fmaxf(fmaxf(t0,t1), fmaxf(t2,t3));
    float e0=expf(t0-m), e1=expf(t1-m), e2=expf(t2-m), e3=expf(t3-m);
    float inv = 1.0f/(e0+e1+e2+e3);
    float s0=e0*inv, s1=e1*inv, s2=e2*inv, s3=e3*inv;

    int idx = blockIdx.x*256 + threadIdx.x;      // B*64 threads, 4 d's each
    int b  = idx >> 6;
    int d4 = (idx & 63) << 2;
    size_t src = (size_t)b*256 + d4;
    float4 a0 = *reinterpret_cast<const float4*>(w0 + src);
    float4 a1 = *reinterpret_cast<const float4*>(w1 + src);
    float4 a2 = *reinterpret_cast<const float4*>(w2 + src);
    float4 a3 = *reinterpret_cast<const float4*>(w3 + src);
    size_t dst = (size_t)b*1024 + d4;
    ushort4 o;
    o.x=f2bf(a0.x*s0); o.y=f2bf(a0.y*s0); o.z=f2bf(a0.z*s0); o.w=f2bf(a0.w*s0);
    *reinterpret_cast<ushort4*>(wcat + dst) = o;
    o.x=f2bf(a1.x*s1); o.y=f2bf(a1.y*s1); o.z=f2bf(a1.z*s1); o.w=f2bf(a1.w*s1);
    *reinterpret_cast<ushort4*>(wcat + dst + 256) = o;
    o.x=f2bf(a2.x*s2); o.y=f2bf(a2.y*s2); o.z=f2bf(a2.z*s2); o.w=f2bf(a2.w*s2);
    *reinterpret_cast<ushort4*>(wcat + dst + 512) = o;
    o.x=f2bf(a3.x*s3); o.y=f2bf(a3.y*s3); o.z=f2bf(a3.z*s3); o.w=f2bf(a3.w*s3);
    *reinterpret_cast<ushort4*>(wcat + dst + 768) = o;
}

// ---------------- weight fp32 -> bf16 conversion ----------------
__global__ __launch_bounds__(256) void conv1_kernel(const float* __restrict__ s, u16* __restrict__ d){
    int i = blockIdx.x*256 + threadIdx.x;
    float4 v = reinterpret_cast<const float4*>(s)[i];
    ushort4 o; o.x=f2bf(v.x); o.y=f2bf(v.y); o.z=f2bf(v.z); o.w=f2bf(v.w);
    reinterpret_cast<ushort4*>(d)[i] = o;
}

__global__ __launch_bounds__(256) void conv2_kernel(
    const float* __restrict__ s0, u16* __restrict__ d0,   // out_proj 16384 chunks
    const float* __restrict__ s1, u16* __restrict__ d1,   // f1       262144
    const float* __restrict__ s2, u16* __restrict__ d2,   // f2       131072
    const float* __restrict__ s3, u16* __restrict__ d3)   // a1       32768
{
    int i = blockIdx.x*256 + threadIdx.x;
    const float* s; u16* d; int off;
    if      (i < 16384) { s=s0; d=d0; off=i; }
    else if (i < 278528){ s=s1; d=d1; off=i-16384; }
    else if (i < 409600){ s=s2; d=d2; off=i-278528; }
    else                { s=s3; d=d3; off=i-409600; }
    float4 v = reinterpret_cast<const float4*>(s)[off];
    ushort4 o; o.x=f2bf(v.x); o.y=f2bf(v.y); o.z=f2bf(v.z); o.w=f2bf(v.w);
    reinterpret_cast<ushort4*>(d)[off] = o;
}

// ---------------- 128x128 MFMA GEMM (kept for N<=256 GEMMs) ----------------
template<int ACT>
__global__ __launch_bounds__(256) void mgemm_kernel(
    const u16* __restrict__ A, int lda,
    const u16* __restrict__ W, int ldw,
    const float* __restrict__ bias,
    u16* __restrict__ C, int ldc, int K)
{
    __shared__ __align__(16) u16 sA[4096];   // [128][32]
    __shared__ __align__(16) u16 sB[4096];   // [128][32]

    const int tid  = threadIdx.x;
    const int lane = tid & 63;
    const int wid  = tid >> 6;
    const int wr   = wid >> 1, wc = wid & 1;
    const int row0 = blockIdx.x << 7, col0 = blockIdx.y << 7;

    const int e0 = tid << 3,          r0s = e0 >> 5, c0s = e0 & 31;
    const int e1 = (256 + tid) << 3,  r1s = e1 >> 5, c1s = e1 & 31;
    const u16* gA0 = A + (size_t)(row0 + r0s)*lda + c0s;
    const u16* gA1 = A + (size_t)(row0 + r1s)*lda + c1s;
    const u16* gB0 = W + (size_t)(col0 + r0s)*ldw + c0s;
    const u16* gB1 = W + (size_t)(col0 + r1s)*ldw + c1s;
    u16* lA0 = sA + (wid << 9);
    u16* lA1 = sA + 2048 + (wid << 9);
    u16* lB0 = sB + (wid << 9);
    u16* lB1 = sB + 2048 + (wid << 9);

    const int la  = lane & 15;
    const int lk  = (lane >> 4) << 3;
    const int hi4 = (lane >> 4) << 2;
    const u16* rA = sA + (((wr << 6) + la) << 5) + lk;
    const u16* rB = sB + (((wc << 6) + la) << 5) + lk;

    f32x4 acc[4][4];
    {
        f32x4 binit[4];
        #pragma unroll
        for (int n=0;n<4;n++){
            float4 b4 = *reinterpret_cast<const float4*>(bias + col0 + (wc<<6) + (n<<4) + hi4);
            binit[n] = (f32x4){b4.x, b4.y, b4.z, b4.w};
        }
        #pragma unroll
        for (int m=0;m<4;m++)
            #pragma unroll
            for (int n=0;n<4;n++) acc[m][n] = binit[n];
    }

    for (int k0 = 0; k0 < K; k0 += 32){
        gload16(gA0 + k0, lA0);
        gload16(gA1 + k0, lA1);
        gload16(gB0 + k0, lB0);
        gload16(gB1 + k0, lB1);
        __syncthreads();
        bf16x8 af[4], bf[4];
        #pragma unroll
        for (int m=0;m<4;m++) af[m] = *reinterpret_cast<const bf16x8*>(rA + (m << 9));
        #pragma unroll
        for (int n=0;n<4;n++) bf[n] = *reinterpret_cast<const bf16x8*>(rB + (n << 9));
        #pragma unroll
        for (int m=0;m<4;m++)
            #pragma unroll
            for (int n=0;n<4;n++)
                acc[m][n] = __builtin_amdgcn_mfma_f32_16x16x32_bf16(bf[n], af[m], acc[m][n], 0, 0, 0);
        __syncthreads();
    }

    #pragma unroll
    for (int m=0;m<4;m++){
        const int grow = row0 + (wr << 6) + (m << 4) + la;
        u16* crow = C + (size_t)grow*ldc + col0 + (wc << 6) + hi4;
        #pragma unroll
        for (int n=0;n<4;n++){
            f32x4 v = acc[m][n];
            float x0=v[0], x1=v[1], x2=v[2], x3=v[3];
            if (ACT == 1){ x0=gelu_f(x0); x1=gelu_f(x1); x2=gelu_f(x2); x3=gelu_f(x3); }
            ushort4 o; o.x=f2bf(x0); o.y=f2bf(x1); o.z=f2bf(x2); o.w=f2bf(x3);
            *reinterpret_cast<ushort4*>(crow + (n << 4)) = o;
        }
    }
}

// ---------------- 256x256 MFMA GEMM, BK=32, 2-deep LDS ring (64KiB -> 2 blocks/CU), counted vmcnt ----------------
// 512 threads = 8 waves (2 Mx4 N); per-wave out 128x64 (8x4 frags).
// Swizzle: LDS(row, slot) holds global k-block (slot ^ ((row>>1)&3)) -> ds_read 2-way conflicts (free).
// Staged via global_load_lds with inverse-permuted global source (linear LDS dest).
template<int ACT>
__global__ __launch_bounds__(512) void gemm256_kernel(
    const u16* __restrict__ A, int lda,
    const u16* __restrict__ W, int ldw,
    const float* __restrict__ bias,
    u16* __restrict__ C, int ldc, int K)
{
    __shared__ __align__(16) u16 sT[32768];   // 2 ring slots x (A[256][32] | B[256][32])

    const int tid  = threadIdx.x;
    const int lane = tid & 63;
    const int wid  = tid >> 6;            // 0..7
    const int wr   = wid >> 2;            // 0..1  (M half)
    const int wc   = wid & 3;             // 0..3  (N quarter)
    const int row0 = blockIdx.x << 8, col0 = blockIdx.y << 8;

    // ---- staging addresses (2 chunks of A + 2 of B per wave per tile) ----
    // chunk c covers tile rows [16c,16c+16); lane i -> row_local i>>2, phys slot i&3
    // phys slot s holds global k-block s ^ ((row>>1)&3)
    const int rA0 = ((wid<<1)    )*16 + (lane>>2);
    const int rA1 = ((wid<<1) + 1)*16 + (lane>>2);
    const int sw0 = ((lane&3) ^ ((rA0>>1)&3)) << 3;
    const int sw1 = ((lane&3) ^ ((rA1>>1)&3)) << 3;
    const u16* pA0 = A + (size_t)(row0 + rA0)*lda + sw0;
    const u16* pA1 = A + (size_t)(row0 + rA1)*lda + sw1;
    const u16* pB0 = W + (size_t)(col0 + rA0)*ldw + sw0;
    const u16* pB1 = W + (size_t)(col0 + rA1)*ldw + sw1;

    // ---- ds_read addressing ----
    const int la  = lane & 15;
    const int sr  = lane >> 4;                  // desired k-block
    const int swze = (sr ^ ((la>>1)&3)) << 3;   // swizzled element offset in row
    const int hi4 = sr << 2;

    f32x4 acc[8][4];
    {
        f32x4 binit[4];
        #pragma unroll
        for (int n=0;n<4;n++){
            float4 b4 = *reinterpret_cast<const float4*>(bias + col0 + (wc<<6) + (n<<4) + hi4);
            binit[n] = (f32x4){b4.x, b4.y, b4.z, b4.w};
        }
        #pragma unroll
        for (int m=0;m<8;m++)
            #pragma unroll
            for (int n=0;n<4;n++) acc[m][n] = binit[n];
    }

    auto stage = [&](int t){
        u16* dA = &sT[(t & 1)*16384 + (wid<<10)];
        const int ko = t << 5;
        gload16(pA0 + ko, dA);
        gload16(pA1 + ko, dA + 512);
        gload16(pB0 + ko, dA + 8192);
        gload16(pB1 + ko, dA + 8192 + 512);
    };

    const int NT = K >> 5;
    stage(0);

    for (int t = 0; t < NT; ++t){
        if (t + 1 < NT){
            stage(t + 1);
            asm volatile("s_waitcnt vmcnt(4)" ::: "memory");
        } else {
            asm volatile("s_waitcnt vmcnt(0)" ::: "memory");
        }
        __builtin_amdgcn_s_barrier();
        __builtin_amdgcn_sched_barrier(0);

        const u16* tb = &sT[(t & 1)*16384];
        const u16* rA = tb + (((wr<<7) + la) << 5) + swze;
        const u16* rB = tb + 8192 + (((wc<<6) + la) << 5) + swze;

        bf16x8 af[8], bf[4];
        #pragma unroll
        for (int m=0;m<8;m++) af[m] = *reinterpret_cast<const bf16x8*>(rA + (m << 9));
        #pragma unroll
        for (int n=0;n<4;n++) bf[n] = *reinterpret_cast<const bf16x8*>(rB + (n << 9));

        __builtin_amdgcn_s_setprio(1);
        #pragma unroll
        for (int m=0;m<8;m++)
            #pragma unroll
            for (int n=0;n<4;n++)
                acc[m][n] = __builtin_amdgcn_mfma_f32_16x16x32_bf16(bf[n], af[m], acc[m][n], 0, 0, 0);
        __builtin_amdgcn_s_setprio(0);
        __builtin_amdgcn_sched_barrier(0);
        asm volatile("" ::: "memory");
        __builtin_amdgcn_s_barrier();
    }

    // epilogue: vectorized ushort4 stores
    #pragma unroll
    for (int m=0;m<8;m++){
        const int grow = row0 + (wr << 7) + (m << 4) + la;
        u16* crow = C + (size_t)grow*ldc + col0 + (wc << 6) + hi4;
        #pragma unroll
        for (int n=0;n<4;n++){
            f32x4 v = acc[m][n];
            float x0=v[0], x1=v[1], x2=v[2], x3=v[3];
            if (ACT == 1){ x0=gelu_f(x0); x1=gelu_f(x1); x2=gelu_f(x2); x3=gelu_f(x3); }
            ushort4 o; o.x=f2bf(x0); o.y=f2bf(x1); o.z=f2bf(x2); o.w=f2bf(x3);
            *reinterpret_cast<ushort4*>(crow + (n << 4)) = o;
        }
    }
}

// ---------------- attention (N=4 keys, H=4 heads, DH=64), merged kv layout [b][n][k|v] ----------------
__global__ __launch_bounds__(256) void attn_kernel(
    const u16* __restrict__ q, const u16* __restrict__ kv,
    u16* __restrict__ ctx)
{
    __shared__ float sQ[256], sK[1024], sV[1024], sS[16], sA[16];
    const int b = blockIdx.x, t = threadIdx.x;
    sQ[t] = bf2f(q[(size_t)b*256 + t]);
    #pragma unroll
    for (int n=0;n<4;n++){
        sK[n*256+t] = bf2f(kv[(size_t)b*2048 + n*512 + t]);
        sV[n*256+t] = bf2f(kv[(size_t)b*2048 + n*512 + 256 + t]);
    }
    __syncthreads();
    if (t < 16){
        int h = t>>2, n = t&3;
        float s = 0.f;
        const int o = h*64;
        #pragma unroll
        for (int dh=0; dh<64; ++dh) s += sQ[o+dh]*sK[n*256+o+dh];
        sS[t] = s * 0.125f;   // 1/sqrt(64)
    }
    __syncthreads();
    if (t < 4){
        float a0=sS[t*4+0], a1=sS[t*4+1], a2=sS[t*4+2], a3=sS[t*4+3];
        float m = fmaxf(fmaxf(a0,a1), fmaxf(a2,a3));
        float e0=expf(a0-m), e1=expf(a1-m), e2=expf(a2-m), e3=expf(a3-m);
        float inv = 1.0f/(e0+e1+e2+e3);
        sA[t*4+0]=e0*inv; sA[t*4+1]=e1*inv; sA[t*4+2]=e2*inv; sA[t*4+3]=e3*inv;
    }
    __syncthreads();
    const int h = t>>6;
    float c = sA[h*4+0]*sV[t] + sA[h*4+1]*sV[256+t] + sA[h*4+2]*sV[512+t] + sA[h*4+3]*sV[768+t];
    ctx[(size_t)b*256 + t] = f2bf(c);
}

// ---------------- entry = FiLM(LN(query + attn_out)), overwrites wcat[b][0] ----------------
__global__ __launch_bounds__(256) void lnfilm_kernel(
    u16* __restrict__ wcat, const u16* __restrict__ ao, const float* __restrict__ regime,
    const float* __restrict__ sgw, const float* __restrict__ sgb,
    const float* __restrict__ sbw, const float* __restrict__ sbb,
    const float* __restrict__ g1, const float* __restrict__ b1)
{
    const int b = blockIdx.x, t = threadIdx.x;
    float x = bf2f(wcat[(size_t)b*1024 + t]) + bf2f(ao[(size_t)b*256 + t]);
    float s = x, q = x*x;
    #pragma unroll
    for (int o=32;o;o>>=1){ s += __shfl_xor(s,o); q += __shfl_xor(q,o); }
    __shared__ float rs[4], rq[4];
    if ((t&63)==0){ rs[t>>6]=s; rq[t>>6]=q; }
    __syncthreads();
    s = rs[0]+rs[1]+rs[2]+rs[3];
    q = rq[0]+rq[1]+rq[2]+rq[3];
    float mu  = s*(1.0f/256.0f);
    float var = q*(1.0f/256.0f) - mu*mu;
    float rstd = rsqrtf(var + 1e-5f);
    float r0=regime[b*4+0], r1=regime[b*4+1], r2=regime[b*4+2], r3=regime[b*4+3];
    float gam = r0*sgw[t*4+0]+r1*sgw[t*4+1]+r2*sgw[t*4+2]+r3*sgw[t*4+3]+sgb[t];
    float bet = r0*sbw[t*4+0]+r1*sbw[t*4+1]+r2*sbw[t*4+2]+r3*sbw[t*4+3]+sbb[t];
    float e = ((x-mu)*rstd*g1[t]+b1[t])*(1.0f+gam)+bet;
    wcat[(size_t)b*1024 + t] = f2bf(e);
}

// ---------------- fused = LN(t1) -> f32 out ----------------
__global__ __launch_bounds__(256) void ln2_kernel(
    const u16* __restrict__ t1, const float* __restrict__ g, const float* __restrict__ bt,
    float* __restrict__ out)
{
    const int b = blockIdx.x, t = threadIdx.x;
    float x0 = bf2f(t1[(size_t)b*512 + t]);
    float x1 = bf2f(t1[(size_t)b*512 + 256 + t]);
    float s = x0+x1, q = x0*x0 + x1*x1;
    #pragma unroll
    for (int o=32;o;o>>=1){ s += __shfl_xor(s,o); q += __shfl_xor(q,o); }
    __shared__ float rs[4], rq[4];
    if ((t&63)==0){ rs[t>>6]=s; rq[t>>6]=q; }
    __syncthreads();
    s = rs[0]+rs[1]+rs[2]+rs[3];
    q = rq[0]+rq[1]+rq[2]+rq[3];
    float mu  = s*(1.0f/512.0f);
    float var = q*(1.0f/512.0f) - mu*mu;
    float rstd = rsqrtf(var + 1e-5f);
    out[(size_t)b*512 + t]       = (x0-mu)*rstd*g[t]     + bt[t];
    out[(size_t)b*512 + 256 + t] = (x1-mu)*rstd*g[256+t] + bt[256+t];
}

// ---------------- alignment = sigmoid(a @ a2_w^T + a2_b) ----------------
__global__ __launch_bounds__(64) void a2_kernel(
    const u16* __restrict__ a, const float* __restrict__ a2w, const float* __restrict__ a2b,
    float* __restrict__ out)
{
    const int b = blockIdx.x, t = threadIdx.x;
    float s = bf2f(a[(size_t)b*128 + t])*a2w[t] + bf2f(a[(size_t)b*128 + 64 + t])*a2w[64+t];
    #pragma unroll
    for (int o=32;o;o>>=1) s += __shfl_xor(s,o);
    if (t==0) out[b] = 1.0f/(1.0f+expf(-(s + a2b[0])));
}

extern "C" void kernel_launch(void* const* d_in, const int* in_sizes, int n_in,
                              void* d_out, int out_size, void* d_ws, size_t ws_size,
                              hipStream_t stream) {
    const float* w0   = (const float*)d_in[0];
    const float* w1   = (const float*)d_in[1];
    const float* w2   = (const float*)d_in[2];
    const float* w3   = (const float*)d_in[3];
    const float* regime = (const float*)d_in[4];
    const float* tfw  = (const float*)d_in[5];
    const float* in_proj_w = (const float*)d_in[6];
    const float* in_proj_b = (const float*)d_in[7];
    const float* out_proj_w = (const float*)d_in[8];
    const float* out_proj_b = (const float*)d_in[9];
    const float* ln1_g = (const float*)d_in[10];
    const float* ln1_b = (const float*)d_in[11];
    const float* sg_w = (const float*)d_in[12];
    const float* sg_b = (const float*)d_in[13];
    const float* sb_w = (const float*)d_in[14];
    const float* sb_b = (const float*)d_in[15];
    const float* f1_w = (const float*)d_in[16];
    const float* f1_b = (const float*)d_in[17];
    const float* f2_w = (const float*)d_in[18];
    const float* f2_b = (const float*)d_in[19];
    const float* ln2_g = (const float*)d_in[20];
    const float* ln2_b = (const float*)d_in[21];
    const float* a1_w = (const float*)d_in[22];
    const float* a1_b = (const float*)d_in[23];
    const float* a2_w = (const float*)d_in[24];
    const float* a2_b = (const float*)d_in[25];

    char* ws = (char*)d_ws;
    // layout (bytes): wcat 64MiB | q/ctx 16MiB | kv 128MiB | ao 16MiB  => 224 MiB total
    u16* wcat  = (u16*)(ws);
    u16* qbuf  = (u16*)(ws + 67108864ull);
    u16* kvbuf = (u16*)(ws + 83886080ull);     // B x 4 x [k(256)|v(256)]
    u16* aobuf = (u16*)(ws + 218103808ull);
    // aliases:
    u16* hbuf  = kvbuf;                        // B x 1024 bf16 (after attn): 80..144MiB
    u16* t1buf = (u16*)(ws + 150994944ull);    // B x 512  bf16: 144..176MiB
    u16* abuf  = aobuf;                        // B x 128  bf16 (after ao consumed)
    u16* ipw   = aobuf;                        // in_proj bf16 (384 KiB) - dead before ao written
    u16* wbf   = (u16*)(ws + 184549376ull);    // 176MiB.. (dead kv tail after attn)
    u16* opw   = wbf;                // 65536 elems
    u16* f1w   = wbf + 65536;        // 1048576
    u16* f2w   = wbf + 1114112;      // 524288
    u16* a1w   = wbf + 1638400;      // 131072

    float* out_fused = (float*)d_out;
    float* out_align = (float*)d_out + (size_t)NB*512;

    // 1. weighted (scaled) -> wcat ; in_proj -> bf16
    prep_kernel<<<NB*64/256, 256, 0, stream>>>(w0,w1,w2,w3,tfw,wcat);
    conv1_kernel<<<192, 256, 0, stream>>>(in_proj_w, ipw);
    // 2. q = query @ wq^T + bq
    mgemm_kernel<0><<<dim3(256, 2), 256, 0, stream>>>(wcat, 1024, ipw, 256, in_proj_b, qbuf, 256, 256);
    // 3. kv = weighted @ [wk;wv]^T + b  (M = 4B rows, N = 512)
    gemm256_kernel<0><<<dim3(512, 2), 512, 0, stream>>>(wcat, 256, ipw+65536, 256, in_proj_b+256, kvbuf, 512, 256);
    // 4. attention -> ctx (overwrites qbuf)
    attn_kernel<<<NB, 256, 0, stream>>>(qbuf, kvbuf, qbuf);
    // 4b. remaining weights -> bf16 (into dead kv-tail region)
    conv2_kernel<<<1728, 256, 0, stream>>>(out_proj_w, opw, f1_w, f1w, f2_w, f2w, a1_w, a1w);
    // 5. attn_out = ctx @ out_proj^T + b
    mgemm_kernel<0><<<dim3(256, 2), 256, 0, stream>>>(qbuf, 256, opw, 256, out_proj_b, aobuf, 256, 256);
    // 6. entry = FiLM(LN(query+attn_out)) -> wcat[:,0:256]  (wcat becomes `cat`)
    lnfilm_kernel<<<NB, 256, 0, stream>>>(wcat, aobuf, regime, sg_w, sg_b, sb_w, sb_b, ln1_g, ln1_b);
    // 7. h = gelu(cat @ f1^T + b) -> hbuf
    gemm256_kernel<1><<<dim3(128, 4), 512, 0, stream>>>(wcat, 1024, f1w, 1024, f1_b, hbuf, 1024, 1024);
    // 8. t1 = h @ f2^T + b
    gemm256_kernel<0><<<dim3(128, 2), 512, 0, stream>>>(hbuf, 1024, f2w, 1024, f2_b, t1buf, 512, 1024);
    // 9. fused = LN(t1) -> out
    ln2_kernel<<<NB, 256, 0, stream>>>(t1buf, ln2_g, ln2_b, out_fused);
    // 10. a = gelu(cat @ a1^T + b)
    mgemm_kernel<1><<<dim3(256, 1), 256, 0, stream>>>(wcat, 1024, a1w, 1024, a1_b, abuf, 128, 1024);
    // 11. alignment = sigmoid(a @ a2^T + b)
    a2_kernel<<<NB, 64, 0, stream>>>(abuf, a2_w, a2_b, out_align);
}

// Round 7
// 376.570 us; speedup vs baseline: 5.6975x; 1.0145x over previous
//
#include <hip/hip_runtime.h>
#include <math.h>

#define NB 32768   // batch
// D=256, N=4, OUT=512, H=4, DH=64

typedef unsigned short u16;
typedef __attribute__((ext_vector_type(4))) float f32x4;
typedef __attribute__((ext_vector_type(8))) short bf16x8;

__device__ __forceinline__ float bf2f(u16 u){ return __uint_as_float(((unsigned int)u)<<16); }
__device__ __forceinline__ u16 f2bf(float f){
    unsigned int x = __float_as_uint(f);
    x += 0x7fffu + ((x>>16)&1u);   // round-to-nearest-even
    return (u16)(x>>16);
}
// gelu exact-erf via A&S 7.1.26 (|eps|<=1.5e-7), branchless: rcp + exp + 5 fma
__device__ __forceinline__ float gelu_f(float x){
    float z = fabsf(x) * 0.70710678118654752f;
    float t = __builtin_amdgcn_rcpf(1.0f + 0.3275911f*z);
    float p = t*(0.254829592f + t*(-0.284496736f + t*(1.421413741f + t*(-1.453152027f + t*1.061405429f))));
    float e = __expf(-z*z);
    float erf_abs = 1.0f - p*e;
    float erfv = copysignf(erf_abs, x);
    return 0.5f*x*(1.0f + erfv);
}

__device__ __forceinline__ void gload16(const void* g, void* l){
    __builtin_amdgcn_global_load_lds(
        (const __attribute__((address_space(1))) unsigned int*)g,
        (__attribute__((address_space(3))) unsigned int*)l, 16, 0, 0);
}

// ---------------- prep: wcat[b][n][d] = w_n[b][d] * softmax(tfw)[n]  (bf16) ----------------
__global__ __launch_bounds__(256) void prep_kernel(
    const float* __restrict__ w0, const float* __restrict__ w1,
    const float* __restrict__ w2, const float* __restrict__ w3,
    const float* __restrict__ tfw, u16* __restrict__ wcat)
{
    float t0=tfw[0], t1=tfw[1], t2=tfw[2], t3=tfw[3];
    float m = fmaxf(fmaxf(t0,t1), fmaxf(t2,t3));
    float e0=expf(t0-m), e1=expf(t1-m), e2=expf(t2-m), e3=expf(t3-m);
    float inv = 1.0f/(e0+e1+e2+e3);
    float s0=e0*inv, s1=e1*inv, s2=e2*inv, s3=e3*inv;

    int idx = blockIdx.x*256 + threadIdx.x;      // B*64 threads, 4 d's each
    int b  = idx >> 6;
    int d4 = (idx & 63) << 2;
    size_t src = (size_t)b*256 + d4;
    float4 a0 = *reinterpret_cast<const float4*>(w0 + src);
    float4 a1 = *reinterpret_cast<const float4*>(w1 + src);
    float4 a2 = *reinterpret_cast<const float4*>(w2 + src);
    float4 a3 = *reinterpret_cast<const float4*>(w3 + src);
    size_t dst = (size_t)b*1024 + d4;
    ushort4 o;
    o.x=f2bf(a0.x*s0); o.y=f2bf(a0.y*s0); o.z=f2bf(a0.z*s0); o.w=f2bf(a0.w*s0);
    *reinterpret_cast<ushort4*>(wcat + dst) = o;
    o.x=f2bf(a1.x*s1); o.y=f2bf(a1.y*s1); o.z=f2bf(a1.z*s1); o.w=f2bf(a1.w*s1);
    *reinterpret_cast<ushort4*>(wcat + dst + 256) = o;
    o.x=f2bf(a2.x*s2); o.y=f2bf(a2.y*s2); o.z=f2bf(a2.z*s2); o.w=f2bf(a2.w*s2);
    *reinterpret_cast<ushort4*>(wcat + dst + 512) = o;
    o.x=f2bf(a3.x*s3); o.y=f2bf(a3.y*s3); o.z=f2bf(a3.z*s3); o.w=f2bf(a3.w*s3);
    *reinterpret_cast<ushort4*>(wcat + dst + 768) = o;
}

// ---------------- weight fp32 -> bf16 conversion ----------------
__global__ __launch_bounds__(256) void conv1_kernel(const float* __restrict__ s, u16* __restrict__ d){
    int i = blockIdx.x*256 + threadIdx.x;
    float4 v = reinterpret_cast<const float4*>(s)[i];
    ushort4 o; o.x=f2bf(v.x); o.y=f2bf(v.y); o.z=f2bf(v.z); o.w=f2bf(v.w);
    reinterpret_cast<ushort4*>(d)[i] = o;
}

__global__ __launch_bounds__(256) void conv2_kernel(
    const float* __restrict__ s0, u16* __restrict__ d0,   // out_proj 16384 chunks
    const float* __restrict__ s1, u16* __restrict__ d1,   // f1       262144
    const float* __restrict__ s2, u16* __restrict__ d2,   // f2       131072
    const float* __restrict__ s3, u16* __restrict__ d3)   // a1       32768
{
    int i = blockIdx.x*256 + threadIdx.x;
    const float* s; u16* d; int off;
    if      (i < 16384) { s=s0; d=d0; off=i; }
    else if (i < 278528){ s=s1; d=d1; off=i-16384; }
    else if (i < 409600){ s=s2; d=d2; off=i-278528; }
    else                { s=s3; d=d3; off=i-409600; }
    float4 v = reinterpret_cast<const float4*>(s)[off];
    ushort4 o; o.x=f2bf(v.x); o.y=f2bf(v.y); o.z=f2bf(v.z); o.w=f2bf(v.w);
    reinterpret_cast<ushort4*>(d)[off] = o;
}

// ---------------- 128x128 MFMA GEMM (kept for N<=256 GEMMs) ----------------
template<int ACT>
__global__ __launch_bounds__(256) void mgemm_kernel(
    const u16* __restrict__ A, int lda,
    const u16* __restrict__ W, int ldw,
    const float* __restrict__ bias,
    u16* __restrict__ C, int ldc, int K)
{
    __shared__ __align__(16) u16 sA[4096];   // [128][32]
    __shared__ __align__(16) u16 sB[4096];   // [128][32]

    const int tid  = threadIdx.x;
    const int lane = tid & 63;
    const int wid  = tid >> 6;
    const int wr   = wid >> 1, wc = wid & 1;
    const int row0 = blockIdx.x << 7, col0 = blockIdx.y << 7;

    const int e0 = tid << 3,          r0s = e0 >> 5, c0s = e0 & 31;
    const int e1 = (256 + tid) << 3,  r1s = e1 >> 5, c1s = e1 & 31;
    const u16* gA0 = A + (size_t)(row0 + r0s)*lda + c0s;
    const u16* gA1 = A + (size_t)(row0 + r1s)*lda + c1s;
    const u16* gB0 = W + (size_t)(col0 + r0s)*ldw + c0s;
    const u16* gB1 = W + (size_t)(col0 + r1s)*ldw + c1s;
    u16* lA0 = sA + (wid << 9);
    u16* lA1 = sA + 2048 + (wid << 9);
    u16* lB0 = sB + (wid << 9);
    u16* lB1 = sB + 2048 + (wid << 9);

    const int la  = lane & 15;
    const int lk  = (lane >> 4) << 3;
    const int hi4 = (lane >> 4) << 2;
    const u16* rA = sA + (((wr << 6) + la) << 5) + lk;
    const u16* rB = sB + (((wc << 6) + la) << 5) + lk;

    f32x4 acc[4][4];
    {
        f32x4 binit[4];
        #pragma unroll
        for (int n=0;n<4;n++){
            float4 b4 = *reinterpret_cast<const float4*>(bias + col0 + (wc<<6) + (n<<4) + hi4);
            binit[n] = (f32x4){b4.x, b4.y, b4.z, b4.w};
        }
        #pragma unroll
        for (int m=0;m<4;m++)
            #pragma unroll
            for (int n=0;n<4;n++) acc[m][n] = binit[n];
    }

    for (int k0 = 0; k0 < K; k0 += 32){
        gload16(gA0 + k0, lA0);
        gload16(gA1 + k0, lA1);
        gload16(gB0 + k0, lB0);
        gload16(gB1 + k0, lB1);
        __syncthreads();
        bf16x8 af[4], bf[4];
        #pragma unroll
        for (int m=0;m<4;m++) af[m] = *reinterpret_cast<const bf16x8*>(rA + (m << 9));
        #pragma unroll
        for (int n=0;n<4;n++) bf[n] = *reinterpret_cast<const bf16x8*>(rB + (n << 9));
        #pragma unroll
        for (int m=0;m<4;m++)
            #pragma unroll
            for (int n=0;n<4;n++)
                acc[m][n] = __builtin_amdgcn_mfma_f32_16x16x32_bf16(bf[n], af[m], acc[m][n], 0, 0, 0);
        __syncthreads();
    }

    #pragma unroll
    for (int m=0;m<4;m++){
        const int grow = row0 + (wr << 6) + (m << 4) + la;
        u16* crow = C + (size_t)grow*ldc + col0 + (wc << 6) + hi4;
        #pragma unroll
        for (int n=0;n<4;n++){
            f32x4 v = acc[m][n];
            float x0=v[0], x1=v[1], x2=v[2], x3=v[3];
            if (ACT == 1){ x0=gelu_f(x0); x1=gelu_f(x1); x2=gelu_f(x2); x3=gelu_f(x3); }
            ushort4 o; o.x=f2bf(x0); o.y=f2bf(x1); o.z=f2bf(x2); o.w=f2bf(x3);
            *reinterpret_cast<ushort4*>(crow + (n << 4)) = o;
        }
    }
}

// ---------------- 256x256 MFMA GEMM, BK=64, 2-buf, 4-phase interleave, counted vmcnt ----------------
// 512 threads = 8 waves (2M x 4N); per-wave out 128x64 = 8x4 frags of 16x16x32.
// LDS 128 KiB: buf b: A[256][64] @ b*32768, B[256][64] @ b*32768+16384 (elems).
// Row layout: 8 chunks of 8 elems; phys chunk = chunk ^ (row&7) -> ds_read 2-way (free).
// Stage: linear LDS dest (gload_lds), inverse-permuted per-lane global source (rule 21).
// Phase p of K-tile t: stage half p of tile t+1 -> [p0: vmcnt(2)] -> barrier ->
//   ds_read quad (mh=p&1, ks=p>>1) 8x b128 -> setprio(1) 16 MFMA setprio(0) -> barrier.
template<int ACT>
__global__ __launch_bounds__(512) void gemm256p_kernel(
    const u16* __restrict__ A, int lda,
    const u16* __restrict__ W, int ldw,
    const float* __restrict__ bias,
    u16* __restrict__ C, int ldc, int K)
{
    __shared__ __align__(16) u16 sT[65536];   // 128 KiB

    const int tid  = threadIdx.x;
    const int lane = tid & 63;
    const int wid  = tid >> 6;            // 0..7
    const int wr   = wid >> 2;            // 0..1
    const int wc   = wid & 3;             // 0..3
    const int row0 = blockIdx.x << 8, col0 = blockIdx.y << 8;

    const int la = lane & 15;
    const int hi = lane >> 4;

    f32x4 acc[8][4];
    {
        f32x4 binit[4];
        #pragma unroll
        for (int n=0;n<4;n++){
            float4 b4 = *reinterpret_cast<const float4*>(bias + col0 + (wc<<6) + (n<<4) + (hi<<2));
            binit[n] = (f32x4){b4.x, b4.y, b4.z, b4.w};
        }
        #pragma unroll
        for (int m=0;m<8;m++)
            #pragma unroll
            for (int n=0;n<4;n++) acc[m][n] = binit[n];
    }

    // staging: each wave stages 16 rows (2 gloads of 8 rows) per half; 4 halves: B0,B1,A0,A1
    const int rs = (wid << 4) + (lane >> 3);                 // local row 0..127 within half
    const int cs = ((lane & 7) ^ ((lane >> 3) & 7)) << 3;    // inverse-permuted chunk
    const u16* gA0 = A + (size_t)(row0 + rs)*lda + cs;
    const u16* gA1 = gA0 + (size_t)128*lda;
    const u16* gB0 = W + (size_t)(col0 + rs)*ldw + cs;
    const u16* gB1 = gB0 + (size_t)128*ldw;
    const int ldsw = (wid << 4) * 64;                        // wave's 16-row slice offset (elems)

    // ds_read bases
    const int cph0 = (hi ^ (la & 7)) << 3;                   // phys chunk offset (elems), ks=0
    const u16* rAbase = sT + ((wr << 7) + la)*64;            // + b + m*1024 + chunk
    const u16* rBbase = sT + 16384 + ((wc << 6) + la)*64;    // + b + n*1024 + chunk

    const int NT = K >> 6;

    // prologue: tile 0 -> buf 0 (order B0,B1,A0,A1 to match FIFO accounting)
    gload16(gB0, sT + 16384 + ldsw);          gload16(gB0 + 8*(size_t)ldw, sT + 16384 + ldsw + 512);
    gload16(gB1, sT + 16384 + 8192 + ldsw);   gload16(gB1 + 8*(size_t)ldw, sT + 16384 + 8192 + ldsw + 512);
    gload16(gA0, sT + ldsw);                  gload16(gA0 + 8*(size_t)lda, sT + ldsw + 512);
    gload16(gA1, sT + 8192 + ldsw);           gload16(gA1 + 8*(size_t)lda, sT + 8192 + ldsw + 512);

    for (int t = 0; t < NT; ++t){
        const int b  = (t & 1) << 15;        // elem offset of current buf
        const int bn = b ^ 32768;            // next buf
        const int stg = (t + 1 < NT);
        const int kb = (t + 1) << 6;

#define STAGE_HALF(GP, LD, DOFF) \
        { gload16(GP + kb, sT + bn + (DOFF) + ldsw); \
          gload16(GP + kb + 8*(size_t)(LD), sT + bn + (DOFF) + ldsw + 512); }

#define PHASE(P) { \
        if ((P)==0){ \
            if (stg) { STAGE_HALF(gB0, ldw, 16384) } \
            if (stg) { asm volatile("s_waitcnt vmcnt(2)" ::: "memory"); } \
            else     { asm volatile("s_waitcnt vmcnt(0)" ::: "memory"); } \
        } \
        if ((P)==1 && stg) { STAGE_HALF(gB1, ldw, 16384 + 8192) } \
        if ((P)==2 && stg) { STAGE_HALF(gA0, lda, 0) } \
        if ((P)==3 && stg) { STAGE_HALF(gA1, lda, 8192) } \
        asm volatile("" ::: "memory"); \
        __builtin_amdgcn_s_barrier(); \
        __builtin_amdgcn_sched_barrier(0); \
        asm volatile("" ::: "memory"); \
        { \
            const int co = cph0 ^ (((P)>>1) << 5); \
            const u16* rA = rAbase + b + (((P)&1) << 12) + co; \
            const u16* rB = rBbase + b + co; \
            bf16x8 af0 = *reinterpret_cast<const bf16x8*>(rA); \
            bf16x8 af1 = *reinterpret_cast<const bf16x8*>(rA + 1024); \
            bf16x8 af2 = *reinterpret_cast<const bf16x8*>(rA + 2048); \
            bf16x8 af3 = *reinterpret_cast<const bf16x8*>(rA + 3072); \
            bf16x8 bf0 = *reinterpret_cast<const bf16x8*>(rB); \
            bf16x8 bf1 = *reinterpret_cast<const bf16x8*>(rB + 1024); \
            bf16x8 bf2 = *reinterpret_cast<const bf16x8*>(rB + 2048); \
            bf16x8 bf3 = *reinterpret_cast<const bf16x8*>(rB + 3072); \
            const int mb = ((P)&1) << 2; \
            __builtin_amdgcn_s_setprio(1); \
            acc[mb+0][0] = __builtin_amdgcn_mfma_f32_16x16x32_bf16(bf0, af0, acc[mb+0][0], 0,0,0); \
            acc[mb+0][1] = __builtin_amdgcn_mfma_f32_16x16x32_bf16(bf1, af0, acc[mb+0][1], 0,0,0); \
            acc[mb+0][2] = __builtin_amdgcn_mfma_f32_16x16x32_bf16(bf2, af0, acc[mb+0][2], 0,0,0); \
            acc[mb+0][3] = __builtin_amdgcn_mfma_f32_16x16x32_bf16(bf3, af0, acc[mb+0][3], 0,0,0); \
            acc[mb+1][0] = __builtin_amdgcn_mfma_f32_16x16x32_bf16(bf0, af1, acc[mb+1][0], 0,0,0); \
            acc[mb+1][1] = __builtin_amdgcn_mfma_f32_16x16x32_bf16(bf1, af1, acc[mb+1][1], 0,0,0); \
            acc[mb+1][2] = __builtin_amdgcn_mfma_f32_16x16x32_bf16(bf2, af1, acc[mb+1][2], 0,0,0); \
            acc[mb+1][3] = __builtin_amdgcn_mfma_f32_16x16x32_bf16(bf3, af1, acc[mb+1][3], 0,0,0); \
            acc[mb+2][0] = __builtin_amdgcn_mfma_f32_16x16x32_bf16(bf0, af2, acc[mb+2][0], 0,0,0); \
            acc[mb+2][1] = __builtin_amdgcn_mfma_f32_16x16x32_bf16(bf1, af2, acc[mb+2][1], 0,0,0); \
            acc[mb+2][2] = __builtin_amdgcn_mfma_f32_16x16x32_bf16(bf2, af2, acc[mb+2][2], 0,0,0); \
            acc[mb+2][3] = __builtin_amdgcn_mfma_f32_16x16x32_bf16(bf3, af2, acc[mb+2][3], 0,0,0); \
            acc[mb+3][0] = __builtin_amdgcn_mfma_f32_16x16x32_bf16(bf0, af3, acc[mb+3][0], 0,0,0); \
            acc[mb+3][1] = __builtin_amdgcn_mfma_f32_16x16x32_bf16(bf1, af3, acc[mb+3][1], 0,0,0); \
            acc[mb+3][2] = __builtin_amdgcn_mfma_f32_16x16x32_bf16(bf2, af3, acc[mb+3][2], 0,0,0); \
            acc[mb+3][3] = __builtin_amdgcn_mfma_f32_16x16x32_bf16(bf3, af3, acc[mb+3][3], 0,0,0); \
            __builtin_amdgcn_s_setprio(0); \
        } \
        __builtin_amdgcn_sched_barrier(0); \
        asm volatile("" ::: "memory"); \
        __builtin_amdgcn_s_barrier(); }

        PHASE(0)
        PHASE(1)
        PHASE(2)
        PHASE(3)
#undef PHASE
#undef STAGE_HALF
    }

    // epilogue: vectorized ushort4 stores
    #pragma unroll
    for (int m=0;m<8;m++){
        const int grow = row0 + (wr << 7) + (m << 4) + la;
        u16* crow = C + (size_t)grow*ldc + col0 + (wc << 6) + (hi << 2);
        #pragma unroll
        for (int n=0;n<4;n++){
            f32x4 v = acc[m][n];
            float x0=v[0], x1=v[1], x2=v[2], x3=v[3];
            if (ACT == 1){ x0=gelu_f(x0); x1=gelu_f(x1); x2=gelu_f(x2); x3=gelu_f(x3); }
            ushort4 o; o.x=f2bf(x0); o.y=f2bf(x1); o.z=f2bf(x2); o.w=f2bf(x3);
            *reinterpret_cast<ushort4*>(crow + (n << 4)) = o;
        }
    }
}

// ---------------- attention (N=4 keys, H=4 heads, DH=64), merged kv layout [b][n][k|v] ----------------
__global__ __launch_bounds__(256) void attn_kernel(
    const u16* __restrict__ q, const u16* __restrict__ kv,
    u16* __restrict__ ctx)
{
    __shared__ float sQ[256], sK[1024], sV[1024], sS[16], sA[16];
    const int b = blockIdx.x, t = threadIdx.x;
    sQ[t] = bf2f(q[(size_t)b*256 + t]);
    #pragma unroll
    for (int n=0;n<4;n++){
        sK[n*256+t] = bf2f(kv[(size_t)b*2048 + n*512 + t]);
        sV[n*256+t] = bf2f(kv[(size_t)b*2048 + n*512 + 256 + t]);
    }
    __syncthreads();
    if (t < 16){
        int h = t>>2, n = t&3;
        float s = 0.f;
        const int o = h*64;
        #pragma unroll
        for (int dh=0; dh<64; ++dh) s += sQ[o+dh]*sK[n*256+o+dh];
        sS[t] = s * 0.125f;   // 1/sqrt(64)
    }
    __syncthreads();
    if (t < 4){
        float a0=sS[t*4+0], a1=sS[t*4+1], a2=sS[t*4+2], a3=sS[t*4+3];
        float m = fmaxf(fmaxf(a0,a1), fmaxf(a2,a3));
        float e0=expf(a0-m), e1=expf(a1-m), e2=expf(a2-m), e3=expf(a3-m);
        float inv = 1.0f/(e0+e1+e2+e3);
        sA[t*4+0]=e0*inv; sA[t*4+1]=e1*inv; sA[t*4+2]=e2*inv; sA[t*4+3]=e3*inv;
    }
    __syncthreads();
    const int h = t>>6;
    float c = sA[h*4+0]*sV[t] + sA[h*4+1]*sV[256+t] + sA[h*4+2]*sV[512+t] + sA[h*4+3]*sV[768+t];
    ctx[(size_t)b*256 + t] = f2bf(c);
}

// ---------------- entry = FiLM(LN(query + attn_out)), overwrites wcat[b][0] ----------------
__global__ __launch_bounds__(256) void lnfilm_kernel(
    u16* __restrict__ wcat, const u16* __restrict__ ao, const float* __restrict__ regime,
    const float* __restrict__ sgw, const float* __restrict__ sgb,
    const float* __restrict__ sbw, const float* __restrict__ sbb,
    const float* __restrict__ g1, const float* __restrict__ b1)
{
    const int b = blockIdx.x, t = threadIdx.x;
    float x = bf2f(wcat[(size_t)b*1024 + t]) + bf2f(ao[(size_t)b*256 + t]);
    float s = x, q = x*x;
    #pragma unroll
    for (int o=32;o;o>>=1){ s += __shfl_xor(s,o); q += __shfl_xor(q,o); }
    __shared__ float rs[4], rq[4];
    if ((t&63)==0){ rs[t>>6]=s; rq[t>>6]=q; }
    __syncthreads();
    s = rs[0]+rs[1]+rs[2]+rs[3];
    q = rq[0]+rq[1]+rq[2]+rq[3];
    float mu  = s*(1.0f/256.0f);
    float var = q*(1.0f/256.0f) - mu*mu;
    float rstd = rsqrtf(var + 1e-5f);
    float r0=regime[b*4+0], r1=regime[b*4+1], r2=regime[b*4+2], r3=regime[b*4+3];
    float gam = r0*sgw[t*4+0]+r1*sgw[t*4+1]+r2*sgw[t*4+2]+r3*sgw[t*4+3]+sgb[t];
    float bet = r0*sbw[t*4+0]+r1*sbw[t*4+1]+r2*sbw[t*4+2]+r3*sbw[t*4+3]+sbb[t];
    float e = ((x-mu)*rstd*g1[t]+b1[t])*(1.0f+gam)+bet;
    wcat[(size_t)b*1024 + t] = f2bf(e);
}

// ---------------- fused = LN(t1) -> f32 out ----------------
__global__ __launch_bounds__(256) void ln2_kernel(
    const u16* __restrict__ t1, const float* __restrict__ g, const float* __restrict__ bt,
    float* __restrict__ out)
{
    const int b = blockIdx.x, t = threadIdx.x;
    float x0 = bf2f(t1[(size_t)b*512 + t]);
    float x1 = bf2f(t1[(size_t)b*512 + 256 + t]);
    float s = x0+x1, q = x0*x0 + x1*x1;
    #pragma unroll
    for (int o=32;o;o>>=1){ s += __shfl_xor(s,o); q += __shfl_xor(q,o); }
    __shared__ float rs[4], rq[4];
    if ((t&63)==0){ rs[t>>6]=s; rq[t>>6]=q; }
    __syncthreads();
    s = rs[0]+rs[1]+rs[2]+rs[3];
    q = rq[0]+rq[1]+rq[2]+rq[3];
    float mu  = s*(1.0f/512.0f);
    float var = q*(1.0f/512.0f) - mu*mu;
    float rstd = rsqrtf(var + 1e-5f);
    out[(size_t)b*512 + t]       = (x0-mu)*rstd*g[t]     + bt[t];
    out[(size_t)b*512 + 256 + t] = (x1-mu)*rstd*g[256+t] + bt[256+t];
}

// ---------------- alignment = sigmoid(a @ a2_w^T + a2_b) ----------------
__global__ __launch_bounds__(64) void a2_kernel(
    const u16* __restrict__ a, const float* __restrict__ a2w, const float* __restrict__ a2b,
    float* __restrict__ out)
{
    const int b = blockIdx.x, t = threadIdx.x;
    float s = bf2f(a[(size_t)b*128 + t])*a2w[t] + bf2f(a[(size_t)b*128 + 64 + t])*a2w[64+t];
    #pragma unroll
    for (int o=32;o;o>>=1) s += __shfl_xor(s,o);
    if (t==0) out[b] = 1.0f/(1.0f+expf(-(s + a2b[0])));
}

extern "C" void kernel_launch(void* const* d_in, const int* in_sizes, int n_in,
                              void* d_out, int out_size, void* d_ws, size_t ws_size,
                              hipStream_t stream) {
    const float* w0   = (const float*)d_in[0];
    const float* w1   = (const float*)d_in[1];
    const float* w2   = (const float*)d_in[2];
    const float* w3   = (const float*)d_in[3];
    const float* regime = (const float*)d_in[4];
    const float* tfw  = (const float*)d_in[5];
    const float* in_proj_w = (const float*)d_in[6];
    const float* in_proj_b = (const float*)d_in[7];
    const float* out_proj_w = (const float*)d_in[8];
    const float* out_proj_b = (const float*)d_in[9];
    const float* ln1_g = (const float*)d_in[10];
    const float* ln1_b = (const float*)d_in[11];
    const float* sg_w = (const float*)d_in[12];
    const float* sg_b = (const float*)d_in[13];
    const float* sb_w = (const float*)d_in[14];
    const float* sb_b = (const float*)d_in[15];
    const float* f1_w = (const float*)d_in[16];
    const float* f1_b = (const float*)d_in[17];
    const float* f2_w = (const float*)d_in[18];
    const float* f2_b = (const float*)d_in[19];
    const float* ln2_g = (const float*)d_in[20];
    const float* ln2_b = (const float*)d_in[21];
    const float* a1_w = (const float*)d_in[22];
    const float* a1_b = (const float*)d_in[23];
    const float* a2_w = (const float*)d_in[24];
    const float* a2_b = (const float*)d_in[25];

    char* ws = (char*)d_ws;
    // layout (bytes): wcat 64MiB | q/ctx 16MiB | kv 128MiB | ao 16MiB  => 224 MiB total
    u16* wcat  = (u16*)(ws);
    u16* qbuf  = (u16*)(ws + 67108864ull);
    u16* kvbuf = (u16*)(ws + 83886080ull);     // B x 4 x [k(256)|v(256)]
    u16* aobuf = (u16*)(ws + 218103808ull);
    // aliases:
    u16* hbuf  = kvbuf;                        // B x 1024 bf16 (after attn): 80..144MiB
    u16* t1buf = (u16*)(ws + 150994944ull);    // B x 512  bf16: 144..176MiB
    u16* abuf  = aobuf;                        // B x 128  bf16 (after ao consumed)
    u16* ipw   = aobuf;                        // in_proj bf16 (384 KiB) - dead before ao written
    u16* wbf   = (u16*)(ws + 184549376ull);    // 176MiB.. (dead kv tail after attn)
    u16* opw   = wbf;                // 65536 elems
    u16* f1w   = wbf + 65536;        // 1048576
    u16* f2w   = wbf + 1114112;      // 524288
    u16* a1w   = wbf + 1638400;      // 131072

    float* out_fused = (float*)d_out;
    float* out_align = (float*)d_out + (size_t)NB*512;

    // 1. weighted (scaled) -> wcat ; in_proj -> bf16
    prep_kernel<<<NB*64/256, 256, 0, stream>>>(w0,w1,w2,w3,tfw,wcat);
    conv1_kernel<<<192, 256, 0, stream>>>(in_proj_w, ipw);
    // 2. q = query @ wq^T + bq
    mgemm_kernel<0><<<dim3(256, 2), 256, 0, stream>>>(wcat, 1024, ipw, 256, in_proj_b, qbuf, 256, 256);
    // 3. kv = weighted @ [wk;wv]^T + b  (M = 4B rows, N = 512)
    gemm256p_kernel<0><<<dim3(512, 2), 512, 0, stream>>>(wcat, 256, ipw+65536, 256, in_proj_b+256, kvbuf, 512, 256);
    // 4. attention -> ctx (overwrites qbuf)
    attn_kernel<<<NB, 256, 0, stream>>>(qbuf, kvbuf, qbuf);
    // 4b. remaining weights -> bf16 (into dead kv-tail region)
    conv2_kernel<<<1728, 256, 0, stream>>>(out_proj_w, opw, f1_w, f1w, f2_w, f2w, a1_w, a1w);
    // 5. attn_out = ctx @ out_proj^T + b
    mgemm_kernel<0><<<dim3(256, 2), 256, 0, stream>>>(qbuf, 256, opw, 256, out_proj_b, aobuf, 256, 256);
    // 6. entry = FiLM(LN(query+attn_out)) -> wcat[:,0:256]  (wcat becomes `cat`)
    lnfilm_kernel<<<NB, 256, 0, stream>>>(wcat, aobuf, regime, sg_w, sg_b, sb_w, sb_b, ln1_g, ln1_b);
    // 7. h = gelu(cat @ f1^T + b) -> hbuf
    gemm256p_kernel<1><<<dim3(128, 4), 512, 0, stream>>>(wcat, 1024, f1w, 1024, f1_b, hbuf, 1024, 1024);
    // 8. t1 = h @ f2^T + b
    gemm256p_kernel<0><<<dim3(128, 2), 512, 0, stream>>>(hbuf, 1024, f2w, 1024, f2_b, t1buf, 512, 1024);
    // 9. fused = LN(t1) -> out
    ln2_kernel<<<NB, 256, 0, stream>>>(t1buf, ln2_g, ln2_b, out_fused);
    // 10. a = gelu(cat @ a1^T + b)
    mgemm_kernel<1><<<dim3(256, 1), 256, 0, stream>>>(wcat, 1024, a1w, 1024, a1_b, abuf, 128, 1024);
    // 11. alignment = sigmoid(a @ a2^T + b)
    a2_kernel<<<NB, 64, 0, stream>>>(abuf, a2_w, a2_b, out_align);
}

// Round 8
// 356.992 us; speedup vs baseline: 6.0100x; 1.0548x over previous
//
#include <hip/hip_runtime.h>
#include <math.h>

#define NB 32768   // batch
// D=256, N=4, OUT=512, H=4, DH=64

typedef unsigned short u16;
typedef __attribute__((ext_vector_type(4))) float f32x4;
typedef __attribute__((ext_vector_type(8))) short bf16x8;

__device__ __forceinline__ float bf2f(u16 u){ return __uint_as_float(((unsigned int)u)<<16); }
__device__ __forceinline__ u16 f2bf(float f){
    unsigned int x = __float_as_uint(f);
    x += 0x7fffu + ((x>>16)&1u);   // round-to-nearest-even
    return (u16)(x>>16);
}
// gelu exact-erf via A&S 7.1.26 (|eps|<=1.5e-7), branchless: rcp + exp + 5 fma
__device__ __forceinline__ float gelu_f(float x){
    float z = fabsf(x) * 0.70710678118654752f;
    float t = __builtin_amdgcn_rcpf(1.0f + 0.3275911f*z);
    float p = t*(0.254829592f + t*(-0.284496736f + t*(1.421413741f + t*(-1.453152027f + t*1.061405429f))));
    float e = __expf(-z*z);
    float erf_abs = 1.0f - p*e;
    float erfv = copysignf(erf_abs, x);
    return 0.5f*x*(1.0f + erfv);
}

__device__ __forceinline__ void gload16(const void* g, void* l){
    __builtin_amdgcn_global_load_lds(
        (const __attribute__((address_space(1))) unsigned int*)g,
        (__attribute__((address_space(3))) unsigned int*)l, 16, 0, 0);
}

// ---------------- prep (scale w0..w3 by softmax(tfw)) + all weight fp32->bf16 conversions ----------------
__global__ __launch_bounds__(256) void prepconv_kernel(
    const float* __restrict__ w0, const float* __restrict__ w1,
    const float* __restrict__ w2, const float* __restrict__ w3,
    const float* __restrict__ tfw, u16* __restrict__ wcat,
    const float* __restrict__ ipw_s, u16* __restrict__ ipw_d,
    const float* __restrict__ op_s,  u16* __restrict__ op_d,
    const float* __restrict__ f1_s,  u16* __restrict__ f1_d,
    const float* __restrict__ f2_s,  u16* __restrict__ f2_d,
    const float* __restrict__ a1_s,  u16* __restrict__ a1_d)
{
    const int blk = blockIdx.x, tid = threadIdx.x;
    if (blk < 8192){
        float t0=tfw[0], t1=tfw[1], t2=tfw[2], t3=tfw[3];
        float m = fmaxf(fmaxf(t0,t1), fmaxf(t2,t3));
        float e0=expf(t0-m), e1=expf(t1-m), e2=expf(t2-m), e3=expf(t3-m);
        float inv = 1.0f/(e0+e1+e2+e3);
        float s0=e0*inv, s1=e1*inv, s2=e2*inv, s3=e3*inv;

        int idx = blk*256 + tid;
        int b  = idx >> 6;
        int d4 = (idx & 63) << 2;
        size_t src = (size_t)b*256 + d4;
        float4 a0 = *reinterpret_cast<const float4*>(w0 + src);
        float4 a1 = *reinterpret_cast<const float4*>(w1 + src);
        float4 a2 = *reinterpret_cast<const float4*>(w2 + src);
        float4 a3 = *reinterpret_cast<const float4*>(w3 + src);
        size_t dst = (size_t)b*1024 + d4;
        ushort4 o;
        o.x=f2bf(a0.x*s0); o.y=f2bf(a0.y*s0); o.z=f2bf(a0.z*s0); o.w=f2bf(a0.w*s0);
        *reinterpret_cast<ushort4*>(wcat + dst) = o;
        o.x=f2bf(a1.x*s1); o.y=f2bf(a1.y*s1); o.z=f2bf(a1.z*s1); o.w=f2bf(a1.w*s1);
        *reinterpret_cast<ushort4*>(wcat + dst + 256) = o;
        o.x=f2bf(a2.x*s2); o.y=f2bf(a2.y*s2); o.z=f2bf(a2.z*s2); o.w=f2bf(a2.w*s2);
        *reinterpret_cast<ushort4*>(wcat + dst + 512) = o;
        o.x=f2bf(a3.x*s3); o.y=f2bf(a3.y*s3); o.z=f2bf(a3.z*s3); o.w=f2bf(a3.w*s3);
        *reinterpret_cast<ushort4*>(wcat + dst + 768) = o;
    } else {
        int i = (blk - 8192)*256 + tid;   // float4 index across all weights
        const float* s; u16* d; int off;
        if      (i < 49152)  { s=ipw_s; d=ipw_d; off=i; }
        else if (i < 65536)  { s=op_s;  d=op_d;  off=i-49152; }
        else if (i < 327680) { s=f1_s;  d=f1_d;  off=i-65536; }
        else if (i < 458752) { s=f2_s;  d=f2_d;  off=i-327680; }
        else                 { s=a1_s;  d=a1_d;  off=i-458752; }
        float4 v = reinterpret_cast<const float4*>(s)[off];
        ushort4 o; o.x=f2bf(v.x); o.y=f2bf(v.y); o.z=f2bf(v.z); o.w=f2bf(v.w);
        reinterpret_cast<ushort4*>(d)[off] = o;
    }
}

// ---------------- 128x128 MFMA GEMM (N<=256 GEMMs). ACT: 0 none, 1 gelu, 2 gelu + fused a2 row-dot ----------------
template<int ACT>
__global__ __launch_bounds__(256) void mgemm_kernel(
    const u16* __restrict__ A, int lda,
    const u16* __restrict__ W, int ldw,
    const float* __restrict__ bias,
    u16* __restrict__ C, int ldc, int K,
    const float* __restrict__ a2w, const float* __restrict__ a2b, float* __restrict__ aln)
{
    __shared__ __align__(16) u16 sA[4096];   // [128][32]
    __shared__ __align__(16) u16 sB[4096];   // [128][32]

    const int tid  = threadIdx.x;
    const int lane = tid & 63;
    const int wid  = tid >> 6;
    const int wr   = wid >> 1, wc = wid & 1;
    const int row0 = blockIdx.x << 7, col0 = blockIdx.y << 7;

    const int e0 = tid << 3,          r0s = e0 >> 5, c0s = e0 & 31;
    const int e1 = (256 + tid) << 3,  r1s = e1 >> 5, c1s = e1 & 31;
    const u16* gA0 = A + (size_t)(row0 + r0s)*lda + c0s;
    const u16* gA1 = A + (size_t)(row0 + r1s)*lda + c1s;
    const u16* gB0 = W + (size_t)(col0 + r0s)*ldw + c0s;
    const u16* gB1 = W + (size_t)(col0 + r1s)*ldw + c1s;
    u16* lA0 = sA + (wid << 9);
    u16* lA1 = sA + 2048 + (wid << 9);
    u16* lB0 = sB + (wid << 9);
    u16* lB1 = sB + 2048 + (wid << 9);

    const int la  = lane & 15;
    const int lk  = (lane >> 4) << 3;
    const int hi4 = (lane >> 4) << 2;
    const u16* rA = sA + (((wr << 6) + la) << 5) + lk;
    const u16* rB = sB + (((wc << 6) + la) << 5) + lk;

    f32x4 acc[4][4];
    {
        f32x4 binit[4];
        #pragma unroll
        for (int n=0;n<4;n++){
            float4 b4 = *reinterpret_cast<const float4*>(bias + col0 + (wc<<6) + (n<<4) + hi4);
            binit[n] = (f32x4){b4.x, b4.y, b4.z, b4.w};
        }
        #pragma unroll
        for (int m=0;m<4;m++)
            #pragma unroll
            for (int n=0;n<4;n++) acc[m][n] = binit[n];
    }

    for (int k0 = 0; k0 < K; k0 += 32){
        gload16(gA0 + k0, lA0);
        gload16(gA1 + k0, lA1);
        gload16(gB0 + k0, lB0);
        gload16(gB1 + k0, lB1);
        __syncthreads();
        bf16x8 af[4], bf[4];
        #pragma unroll
        for (int m=0;m<4;m++) af[m] = *reinterpret_cast<const bf16x8*>(rA + (m << 9));
        #pragma unroll
        for (int n=0;n<4;n++) bf[n] = *reinterpret_cast<const bf16x8*>(rB + (n << 9));
        #pragma unroll
        for (int m=0;m<4;m++)
            #pragma unroll
            for (int n=0;n<4;n++)
                acc[m][n] = __builtin_amdgcn_mfma_f32_16x16x32_bf16(bf[n], af[m], acc[m][n], 0, 0, 0);
        __syncthreads();
    }

    if (ACT == 2){
        // fused: alignment[row] = sigmoid( sum_col gelu(val)*a2w[col] + a2b )
        float w4[4][4];
        #pragma unroll
        for (int n=0;n<4;n++){
            float4 t4 = *reinterpret_cast<const float4*>(a2w + (wc<<6) + (n<<4) + hi4);
            w4[n][0]=t4.x; w4[n][1]=t4.y; w4[n][2]=t4.z; w4[n][3]=t4.w;
        }
        float* red = reinterpret_cast<float*>(sA);   // [128 rows][8 slots], 4KB
        #pragma unroll
        for (int m=0;m<4;m++){
            float p = 0.f;
            #pragma unroll
            for (int n=0;n<4;n++){
                f32x4 v = acc[m][n];
                p += gelu_f(v[0])*w4[n][0] + gelu_f(v[1])*w4[n][1]
                   + gelu_f(v[2])*w4[n][2] + gelu_f(v[3])*w4[n][3];
            }
            red[(((wr<<6) + (m<<4) + la) << 3) + (wc<<2) + (lane>>4)] = p;
        }
        __syncthreads();
        if (tid < 128){
            float s = 0.f;
            #pragma unroll
            for (int k2=0;k2<8;k2++) s += red[(tid<<3)+k2];
            aln[row0 + tid] = 1.0f/(1.0f + __expf(-(s + a2b[0])));
        }
        return;
    }

    #pragma unroll
    for (int m=0;m<4;m++){
        const int grow = row0 + (wr << 6) + (m << 4) + la;
        u16* crow = C + (size_t)grow*ldc + col0 + (wc << 6) + hi4;
        #pragma unroll
        for (int n=0;n<4;n++){
            f32x4 v = acc[m][n];
            float x0=v[0], x1=v[1], x2=v[2], x3=v[3];
            if (ACT == 1){ x0=gelu_f(x0); x1=gelu_f(x1); x2=gelu_f(x2); x3=gelu_f(x3); }
            ushort4 o; o.x=f2bf(x0); o.y=f2bf(x1); o.z=f2bf(x2); o.w=f2bf(x3);
            *reinterpret_cast<ushort4*>(crow + (n << 4)) = o;
        }
    }
}

// ---------------- 256x256 MFMA GEMM, BK=64, 2-buf, 4 phases/tile, ONE barrier/phase, pre-barrier ds_reads ----------------
// 512 threads = 8 waves (2M x 4N); per-wave out 128x64 = 8x4 frags of 16x16x32.
// LDS 128 KiB: buf b: A[256][64] @ b, B[256][64] @ b+16384 (elems). Chunk swizzle: phys = logical ^ (row&7).
// Hazard ledger: vmcnt(0)+barrier at p0 makes ALL of tile t CU-visible (p1-3 pre-barrier reads safe);
// stages always write the other buffer; cross-tile WAR ordered by lgkm-before-MFMA[t-1,p3] < barrier[t,0] < stage.
template<int ACT>
__global__ __launch_bounds__(512) void gemm256p_kernel(
    const u16* __restrict__ A, int lda,
    const u16* __restrict__ W, int ldw,
    const float* __restrict__ bias,
    u16* __restrict__ C, int ldc, int K)
{
    __shared__ __align__(16) u16 sT[65536];   // 128 KiB

    const int tid  = threadIdx.x;
    const int lane = tid & 63;
    const int wid  = tid >> 6;            // 0..7
    const int wr   = wid >> 2;            // 0..1
    const int wc   = wid & 3;             // 0..3
    const int row0 = blockIdx.x << 8, col0 = blockIdx.y << 8;

    const int la = lane & 15;
    const int hi = lane >> 4;

    f32x4 acc[8][4];
    {
        f32x4 binit[4];
        #pragma unroll
        for (int n=0;n<4;n++){
            float4 b4 = *reinterpret_cast<const float4*>(bias + col0 + (wc<<6) + (n<<4) + (hi<<2));
            binit[n] = (f32x4){b4.x, b4.y, b4.z, b4.w};
        }
        #pragma unroll
        for (int m=0;m<8;m++)
            #pragma unroll
            for (int n=0;n<4;n++) acc[m][n] = binit[n];
    }

    // staging: wave stages 16 rows (2 gloads x 8 rows) per half; halves: B0,B1,A0,A1
    const int rs = (wid << 4) + (lane >> 3);                 // local row within half
    const int cs = ((lane & 7) ^ ((lane >> 3) & 7)) << 3;    // inverse-permuted chunk
    const u16* gA0 = A + (size_t)(row0 + rs)*lda + cs;
    const u16* gA1 = gA0 + (size_t)128*lda;
    const u16* gB0 = W + (size_t)(col0 + rs)*ldw + cs;
    const u16* gB1 = gB0 + (size_t)128*ldw;
    const int ldsw = (wid << 4) * 64;                        // wave's 16-row slice (elems)

    // ds_read bases
    const int cph0 = (hi ^ (la & 7)) << 3;                   // phys chunk (elems) for ks=0
    const u16* rAbase = sT + ((wr << 7) + la)*64;
    const u16* rBbase = sT + 16384 + ((wc << 6) + la)*64;

    const int NT = K >> 6;

    // prologue: tile 0 -> buf 0 (order B0,B1,A0,A1)
    gload16(gB0, sT + 16384 + ldsw);          gload16(gB0 + 8*(size_t)ldw, sT + 16384 + ldsw + 512);
    gload16(gB1, sT + 24576 + ldsw);          gload16(gB1 + 8*(size_t)ldw, sT + 24576 + ldsw + 512);
    gload16(gA0, sT + ldsw);                  gload16(gA0 + 8*(size_t)lda, sT + ldsw + 512);
    gload16(gA1, sT + 8192 + ldsw);           gload16(gA1 + 8*(size_t)lda, sT + 8192 + ldsw + 512);

#define STG(GP, LD, DOFF) \
        gload16(GP + kb, sT + bn + (DOFF) + ldsw); \
        gload16(GP + kb + 8*(size_t)(LD), sT + bn + (DOFF) + ldsw + 512);

#define DSR(MH, KS) { \
        const int co_ = cph0 ^ ((KS) << 5); \
        const u16* rA_ = rAbase + b + ((MH) << 12) + co_; \
        const u16* rB_ = rBbase + b + co_; \
        af[0] = *reinterpret_cast<const bf16x8*>(rA_); \
        af[1] = *reinterpret_cast<const bf16x8*>(rA_ + 1024); \
        af[2] = *reinterpret_cast<const bf16x8*>(rA_ + 2048); \
        af[3] = *reinterpret_cast<const bf16x8*>(rA_ + 3072); \
        bf[0] = *reinterpret_cast<const bf16x8*>(rB_); \
        bf[1] = *reinterpret_cast<const bf16x8*>(rB_ + 1024); \
        bf[2] = *reinterpret_cast<const bf16x8*>(rB_ + 2048); \
        bf[3] = *reinterpret_cast<const bf16x8*>(rB_ + 3072); }

#define MFMA16(MB) { \
        __builtin_amdgcn_s_setprio(1); \
        _Pragma("unroll") \
        for (int m=0;m<4;m++){ \
            _Pragma("unroll") \
            for (int n=0;n<4;n++) \
                acc[(MB)+m][n] = __builtin_amdgcn_mfma_f32_16x16x32_bf16(bf[n], af[m], acc[(MB)+m][n], 0,0,0); \
        } \
        __builtin_amdgcn_s_setprio(0); }

    for (int t = 0; t < NT; ++t){
        const int b  = (t & 1) << 15;
        const int bn = b ^ 32768;
        const bool stg = (t + 1 < NT);
        const int kb = (t + 1) << 6;
        bf16x8 af[4], bf[4];

        // ---- p0: tile-t fully visible after vmcnt(0)+barrier ----
        asm volatile("s_waitcnt vmcnt(0)" ::: "memory");
        __builtin_amdgcn_s_barrier();
        __builtin_amdgcn_sched_barrier(0);
        DSR(0,0)
        if (stg){ STG(gB0, ldw, 16384) }
        MFMA16(0)
        // ---- p1 ----
        DSR(1,0)
        if (stg){ STG(gB1, ldw, 24576) }
        __builtin_amdgcn_sched_barrier(0);
        __builtin_amdgcn_s_barrier();
        __builtin_amdgcn_sched_barrier(0);
        MFMA16(4)
        // ---- p2 ----
        DSR(0,1)
        if (stg){ STG(gA0, lda, 0) }
        __builtin_amdgcn_sched_barrier(0);
        __builtin_amdgcn_s_barrier();
        __builtin_amdgcn_sched_barrier(0);
        MFMA16(0)
        // ---- p3 ----
        DSR(1,1)
        if (stg){ STG(gA1, lda, 8192) }
        __builtin_amdgcn_sched_barrier(0);
        __builtin_amdgcn_s_barrier();
        __builtin_amdgcn_sched_barrier(0);
        MFMA16(4)
    }
#undef STG
#undef DSR
#undef MFMA16

    // epilogue: vectorized ushort4 stores
    #pragma unroll
    for (int m=0;m<8;m++){
        const int grow = row0 + (wr << 7) + (m << 4) + la;
        u16* crow = C + (size_t)grow*ldc + col0 + (wc << 6) + (hi << 2);
        #pragma unroll
        for (int n=0;n<4;n++){
            f32x4 v = acc[m][n];
            float x0=v[0], x1=v[1], x2=v[2], x3=v[3];
            if (ACT == 1){ x0=gelu_f(x0); x1=gelu_f(x1); x2=gelu_f(x2); x3=gelu_f(x3); }
            ushort4 o; o.x=f2bf(x0); o.y=f2bf(x1); o.z=f2bf(x2); o.w=f2bf(x3);
            *reinterpret_cast<ushort4*>(crow + (n << 4)) = o;
        }
    }
}

// ---------------- attention (N=4 keys, H=4 heads, DH=64), merged kv layout [b][n][k|v] ----------------
__global__ __launch_bounds__(256) void attn_kernel(
    const u16* __restrict__ q, const u16* __restrict__ kv,
    u16* __restrict__ ctx)
{
    __shared__ float sQ[256], sK[1024], sV[1024], sS[16], sA[16];
    const int b = blockIdx.x, t = threadIdx.x;
    sQ[t] = bf2f(q[(size_t)b*256 + t]);
    #pragma unroll
    for (int n=0;n<4;n++){
        sK[n*256+t] = bf2f(kv[(size_t)b*2048 + n*512 + t]);
        sV[n*256+t] = bf2f(kv[(size_t)b*2048 + n*512 + 256 + t]);
    }
    __syncthreads();
    if (t < 16){
        int h = t>>2, n = t&3;
        float s = 0.f;
        const int o = h*64;
        #pragma unroll
        for (int dh=0; dh<64; ++dh) s += sQ[o+dh]*sK[n*256+o+dh];
        sS[t] = s * 0.125f;   // 1/sqrt(64)
    }
    __syncthreads();
    if (t < 4){
        float a0=sS[t*4+0], a1=sS[t*4+1], a2=sS[t*4+2], a3=sS[t*4+3];
        float m = fmaxf(fmaxf(a0,a1), fmaxf(a2,a3));
        float e0=expf(a0-m), e1=expf(a1-m), e2=expf(a2-m), e3=expf(a3-m);
        float inv = 1.0f/(e0+e1+e2+e3);
        sA[t*4+0]=e0*inv; sA[t*4+1]=e1*inv; sA[t*4+2]=e2*inv; sA[t*4+3]=e3*inv;
    }
    __syncthreads();
    const int h = t>>6;
    float c = sA[h*4+0]*sV[t] + sA[h*4+1]*sV[256+t] + sA[h*4+2]*sV[512+t] + sA[h*4+3]*sV[768+t];
    ctx[(size_t)b*256 + t] = f2bf(c);
}

// ---------------- entry = FiLM(LN(query + attn_out)), overwrites wcat[b][0] ----------------
__global__ __launch_bounds__(256) void lnfilm_kernel(
    u16* __restrict__ wcat, const u16* __restrict__ ao, const float* __restrict__ regime,
    const float* __restrict__ sgw, const float* __restrict__ sgb,
    const float* __restrict__ sbw, const float* __restrict__ sbb,
    const float* __restrict__ g1, const float* __restrict__ b1)
{
    const int b = blockIdx.x, t = threadIdx.x;
    float x = bf2f(wcat[(size_t)b*1024 + t]) + bf2f(ao[(size_t)b*256 + t]);
    float s = x, q = x*x;
    #pragma unroll
    for (int o=32;o;o>>=1){ s += __shfl_xor(s,o); q += __shfl_xor(q,o); }
    __shared__ float rs[4], rq[4];
    if ((t&63)==0){ rs[t>>6]=s; rq[t>>6]=q; }
    __syncthreads();
    s = rs[0]+rs[1]+rs[2]+rs[3];
    q = rq[0]+rq[1]+rq[2]+rq[3];
    float mu  = s*(1.0f/256.0f);
    float var = q*(1.0f/256.0f) - mu*mu;
    float rstd = rsqrtf(var + 1e-5f);
    float r0=regime[b*4+0], r1=regime[b*4+1], r2=regime[b*4+2], r3=regime[b*4+3];
    float gam = r0*sgw[t*4+0]+r1*sgw[t*4+1]+r2*sgw[t*4+2]+r3*sgw[t*4+3]+sgb[t];
    float bet = r0*sbw[t*4+0]+r1*sbw[t*4+1]+r2*sbw[t*4+2]+r3*sbw[t*4+3]+sbb[t];
    float e = ((x-mu)*rstd*g1[t]+b1[t])*(1.0f+gam)+bet;
    wcat[(size_t)b*1024 + t] = f2bf(e);
}

// ---------------- fused = LN(t1) -> f32 out ----------------
__global__ __launch_bounds__(256) void ln2_kernel(
    const u16* __restrict__ t1, const float* __restrict__ g, const float* __restrict__ bt,
    float* __restrict__ out)
{
    const int b = blockIdx.x, t = threadIdx.x;
    float x0 = bf2f(t1[(size_t)b*512 + t]);
    float x1 = bf2f(t1[(size_t)b*512 + 256 + t]);
    float s = x0+x1, q = x0*x0 + x1*x1;
    #pragma unroll
    for (int o=32;o;o>>=1){ s += __shfl_xor(s,o); q += __shfl_xor(q,o); }
    __shared__ float rs[4], rq[4];
    if ((t&63)==0){ rs[t>>6]=s; rq[t>>6]=q; }
    __syncthreads();
    s = rs[0]+rs[1]+rs[2]+rs[3];
    q = rq[0]+rq[1]+rq[2]+rq[3];
    float mu  = s*(1.0f/512.0f);
    float var = q*(1.0f/512.0f) - mu*mu;
    float rstd = rsqrtf(var + 1e-5f);
    out[(size_t)b*512 + t]       = (x0-mu)*rstd*g[t]     + bt[t];
    out[(size_t)b*512 + 256 + t] = (x1-mu)*rstd*g[256+t] + bt[256+t];
}

extern "C" void kernel_launch(void* const* d_in, const int* in_sizes, int n_in,
                              void* d_out, int out_size, void* d_ws, size_t ws_size,
                              hipStream_t stream) {
    const float* w0   = (const float*)d_in[0];
    const float* w1   = (const float*)d_in[1];
    const float* w2   = (const float*)d_in[2];
    const float* w3   = (const float*)d_in[3];
    const float* regime = (const float*)d_in[4];
    const float* tfw  = (const float*)d_in[5];
    const float* in_proj_w = (const float*)d_in[6];
    const float* in_proj_b = (const float*)d_in[7];
    const float* out_proj_w = (const float*)d_in[8];
    const float* out_proj_b = (const float*)d_in[9];
    const float* ln1_g = (const float*)d_in[10];
    const float* ln1_b = (const float*)d_in[11];
    const float* sg_w = (const float*)d_in[12];
    const float* sg_b = (const float*)d_in[13];
    const float* sb_w = (const float*)d_in[14];
    const float* sb_b = (const float*)d_in[15];
    const float* f1_w = (const float*)d_in[16];
    const float* f1_b = (const float*)d_in[17];
    const float* f2_w = (const float*)d_in[18];
    const float* f2_b = (const float*)d_in[19];
    const float* ln2_g = (const float*)d_in[20];
    const float* ln2_b = (const float*)d_in[21];
    const float* a1_w = (const float*)d_in[22];
    const float* a1_b = (const float*)d_in[23];
    const float* a2_w = (const float*)d_in[24];
    const float* a2_b = (const float*)d_in[25];

    char* ws = (char*)d_ws;
    // layout (bytes):
    //   wcat   0  .. 64Mi   (B x 1024 bf16)
    //   q/ctx  64 .. 80Mi
    //   kv     80 .. 208Mi  (B x 2048 bf16); post-attn aliases: hbuf 80..144Mi, t1 144..176Mi, ao 176..192Mi
    //   wbf16  208Mi..      (~3.75 MiB of converted weights, written once up front)
    u16* wcat  = (u16*)(ws);
    u16* qbuf  = (u16*)(ws + 67108864ull);
    u16* kvbuf = (u16*)(ws + 83886080ull);
    u16* hbuf  = kvbuf;
    u16* t1buf = (u16*)(ws + 150994944ull);
    u16* aobuf = (u16*)(ws + 184549376ull);
    u16* wb    = (u16*)(ws + 218103808ull);
    u16* ipw = wb;                // 196608 elems
    u16* opw = wb + 196608;       // 65536
    u16* f1w = wb + 262144;       // 1048576
    u16* f2w = wb + 1310720;      // 524288
    u16* a1w = wb + 1835008;      // 131072

    float* out_fused = (float*)d_out;
    float* out_align = (float*)d_out + (size_t)NB*512;

    // 1. prep + all weight conversions (one kernel)
    prepconv_kernel<<<10112, 256, 0, stream>>>(w0,w1,w2,w3,tfw,wcat,
        in_proj_w,ipw, out_proj_w,opw, f1_w,f1w, f2_w,f2w, a1_w,a1w);
    // 2. q = query @ wq^T + bq
    mgemm_kernel<0><<<dim3(256, 2), 256, 0, stream>>>(wcat, 1024, ipw, 256, in_proj_b, qbuf, 256, 256, nullptr, nullptr, nullptr);
    // 3. kv = weighted @ [wk;wv]^T + b  (M = 4B rows, N = 512)
    gemm256p_kernel<0><<<dim3(512, 2), 512, 0, stream>>>(wcat, 256, ipw+65536, 256, in_proj_b+256, kvbuf, 512, 256);
    // 4. attention -> ctx (overwrites qbuf)
    attn_kernel<<<NB, 256, 0, stream>>>(qbuf, kvbuf, qbuf);
    // 5. attn_out = ctx @ out_proj^T + b
    mgemm_kernel<0><<<dim3(256, 2), 256, 0, stream>>>(qbuf, 256, opw, 256, out_proj_b, aobuf, 256, 256, nullptr, nullptr, nullptr);
    // 6. entry = FiLM(LN(query+attn_out)) -> wcat[:,0:256]
    lnfilm_kernel<<<NB, 256, 0, stream>>>(wcat, aobuf, regime, sg_w, sg_b, sb_w, sb_b, ln1_g, ln1_b);
    // 7. h = gelu(cat @ f1^T + b) -> hbuf
    gemm256p_kernel<1><<<dim3(128, 4), 512, 0, stream>>>(wcat, 1024, f1w, 1024, f1_b, hbuf, 1024, 1024);
    // 8. t1 = h @ f2^T + b
    gemm256p_kernel<0><<<dim3(128, 2), 512, 0, stream>>>(hbuf, 1024, f2w, 1024, f2_b, t1buf, 512, 1024);
    // 9. fused = LN(t1) -> out
    ln2_kernel<<<NB, 256, 0, stream>>>(t1buf, ln2_g, ln2_b, out_fused);
    // 10. alignment = sigmoid(gelu(cat @ a1^T + b) @ a2^T + b)  — fused
    mgemm_kernel<2><<<dim3(256, 1), 256, 0, stream>>>(wcat, 1024, a1w, 1024, a1_b, qbuf, 128, 1024, a2_w, a2_b, out_align);
}